// Round 1
// baseline (2196.369 us; speedup 1.0000x reference)
//
#include <hip/hip_runtime.h>
#include <hip/hip_bf16.h>

#define NN 8192
#define EE 262144
#define BB 8
#define LL 1024
#define HH 8
#define DD 256
#define DFFN 2048

// ---------------------------------------------------------------------------
// Generic tiled fp32 GEMM: C[M,N] = A[M,K] @ W[N,K]^T (+bias) (+res) (relu?)
// 64x64 tile, BK=16, 256 threads, 4x4 per thread.
// ---------------------------------------------------------------------------
template<bool BIAS, bool RELU, bool RES>
__global__ __launch_bounds__(256) void gemm_kernel(
    const float* __restrict__ A, const float* __restrict__ W,
    const float* __restrict__ bias, const float* __restrict__ res,
    float* __restrict__ C, int M, int N, int K)
{
    __shared__ float As[16][65];
    __shared__ float Bs[16][65];
    int t  = threadIdx.x;
    int m0 = blockIdx.x * 64;
    int n0 = blockIdx.y * 64;
    int lr = t >> 2;          // 0..63
    int lk = (t & 3) * 4;     // 0,4,8,12
    int ty = t >> 4, tx = t & 15;
    float acc[4][4] = {};
    for (int k0 = 0; k0 < K; k0 += 16) {
        float4 av = *(const float4*)(A + (size_t)(m0 + lr) * K + k0 + lk);
        float4 bv = *(const float4*)(W + (size_t)(n0 + lr) * K + k0 + lk);
        As[lk + 0][lr] = av.x; As[lk + 1][lr] = av.y;
        As[lk + 2][lr] = av.z; As[lk + 3][lr] = av.w;
        Bs[lk + 0][lr] = bv.x; Bs[lk + 1][lr] = bv.y;
        Bs[lk + 2][lr] = bv.z; Bs[lk + 3][lr] = bv.w;
        __syncthreads();
#pragma unroll
        for (int kk = 0; kk < 16; ++kk) {
            float a[4], b[4];
#pragma unroll
            for (int i = 0; i < 4; ++i) a[i] = As[kk][ty * 4 + i];
#pragma unroll
            for (int j = 0; j < 4; ++j) b[j] = Bs[kk][tx * 4 + j];
#pragma unroll
            for (int i = 0; i < 4; ++i)
#pragma unroll
                for (int j = 0; j < 4; ++j)
                    acc[i][j] += a[i] * b[j];
        }
        __syncthreads();
    }
#pragma unroll
    for (int i = 0; i < 4; ++i) {
        int m = m0 + ty * 4 + i;
#pragma unroll
        for (int j = 0; j < 4; ++j) {
            int n = n0 + tx * 4 + j;
            float v = acc[i][j];
            if (BIAS) v += bias[n];
            if (RES)  v += res[(size_t)m * N + n];
            if (RELU) v = fmaxf(v, 0.f);
            C[(size_t)m * N + n] = v;
        }
    }
}

// ---------------------------------------------------------------------------
// GAT: per-(node,head) attention logits a_s, a_d
// ---------------------------------------------------------------------------
__global__ __launch_bounds__(256) void asd_kernel(
    const float* __restrict__ h, const float* __restrict__ atts,
    const float* __restrict__ attd, float* __restrict__ a_s, float* __restrict__ a_d)
{
    int idx = blockIdx.x * 256 + threadIdx.x;   // n*8 + head, 65536 total
    int n = idx >> 3, hh = idx & 7;
    const float* hr = h + (size_t)n * DD + hh * 32;
    const float* sr = atts + hh * 32;
    const float* dr = attd + hh * 32;
    float ss = 0.f, sd = 0.f;
#pragma unroll
    for (int c = 0; c < 32; ++c) { float v = hr[c]; ss += v * sr[c]; sd += v * dr[c]; }
    a_s[idx] = ss; a_d[idx] = sd;
}

// ---------------------------------------------------------------------------
// CSR build (edges + self loops), rebuilt every launch (ws is poisoned)
// ---------------------------------------------------------------------------
__global__ void count_kernel(const int* __restrict__ ei, int* __restrict__ deg)
{
    int e = blockIdx.x * 256 + threadIdx.x;
    if (e >= EE + NN) return;
    int d = (e < EE) ? ei[EE + e] : (e - EE);
    atomicAdd(&deg[d], 1);
}

__global__ __launch_bounds__(1024) void scan_kernel(
    const int* __restrict__ deg, int* __restrict__ rowptr, int* __restrict__ cursor)
{
    __shared__ int part[1024];
    int t = threadIdx.x;
    int base = t * 8;
    int loc[8]; int s = 0;
#pragma unroll
    for (int i = 0; i < 8; ++i) { loc[i] = deg[base + i]; s += loc[i]; }
    part[t] = s;
    __syncthreads();
    for (int off = 1; off < 1024; off <<= 1) {
        int v = (t >= off) ? part[t - off] : 0;
        __syncthreads();
        part[t] += v;
        __syncthreads();
    }
    int run = (t == 0) ? 0 : part[t - 1];
#pragma unroll
    for (int i = 0; i < 8; ++i) { rowptr[base + i] = run; cursor[base + i] = run; run += loc[i]; }
    if (t == 1023) rowptr[NN] = run;
}

__global__ void scatter_kernel(const int* __restrict__ ei, int* __restrict__ cursor,
                               int* __restrict__ col)
{
    int e = blockIdx.x * 256 + threadIdx.x;
    if (e >= EE + NN) return;
    int s, d;
    if (e < EE) { s = ei[e]; d = ei[EE + e]; } else { s = e - EE; d = s; }
    int slot = atomicAdd(&cursor[d], 1);
    col[slot] = s;
}

// ---------------------------------------------------------------------------
// GAT aggregation: one 64-lane wave per dst node. 3 passes over edge list:
// max, sum-exp, weighted accumulate. Epilogue: +bias, relu.
// ---------------------------------------------------------------------------
__global__ __launch_bounds__(256) void gat_agg_kernel(
    const float* __restrict__ hlin, const float* __restrict__ a_s,
    const float* __restrict__ a_d, const int* __restrict__ rowptr,
    const int* __restrict__ col, const float* __restrict__ bias,
    float* __restrict__ out)
{
    int wid = threadIdx.x >> 6, lane = threadIdx.x & 63;
    int dst = blockIdx.x * 4 + wid;
    int start = rowptr[dst], end = rowptr[dst + 1];
    float ad[HH];
#pragma unroll
    for (int h = 0; h < HH; ++h) ad[h] = a_d[(size_t)dst * HH + h];

    float m[HH];
#pragma unroll
    for (int h = 0; h < HH; ++h) m[h] = -1e30f;
    for (int e = start + lane; e < end; e += 64) {
        int s = col[e];
#pragma unroll
        for (int h = 0; h < HH; ++h) {
            float v = a_s[(size_t)s * HH + h] + ad[h];
            v = v > 0.f ? v : 0.2f * v;
            m[h] = fmaxf(m[h], v);
        }
    }
#pragma unroll
    for (int h = 0; h < HH; ++h)
#pragma unroll
        for (int off = 32; off; off >>= 1) m[h] = fmaxf(m[h], __shfl_xor(m[h], off));

    float sm[HH];
#pragma unroll
    for (int h = 0; h < HH; ++h) sm[h] = 0.f;
    for (int e = start + lane; e < end; e += 64) {
        int s = col[e];
#pragma unroll
        for (int h = 0; h < HH; ++h) {
            float v = a_s[(size_t)s * HH + h] + ad[h];
            v = v > 0.f ? v : 0.2f * v;
            sm[h] += __expf(v - m[h]);
        }
    }
#pragma unroll
    for (int h = 0; h < HH; ++h)
#pragma unroll
        for (int off = 32; off; off >>= 1) sm[h] += __shfl_xor(sm[h], off);

    int myh = lane >> 3;          // channel group lane*4 .. lane*4+3 -> head
    float mh = m[myh], sh = sm[myh], adh = ad[myh];
    float4 acc = make_float4(0.f, 0.f, 0.f, 0.f);
    for (int e = start; e < end; ++e) {
        int s = col[e];
        float v = a_s[(size_t)s * HH + myh] + adh;
        v = v > 0.f ? v : 0.2f * v;
        float alpha = __expf(v - mh) / sh;
        float4 hv = *(const float4*)(hlin + (size_t)s * DD + lane * 4);
        acc.x += alpha * hv.x; acc.y += alpha * hv.y;
        acc.z += alpha * hv.z; acc.w += alpha * hv.w;
    }
    float4 bv = *(const float4*)(bias + lane * 4);
    float* op = out + (size_t)dst * DD + lane * 4;
    op[0] = fmaxf(acc.x + bv.x, 0.f);
    op[1] = fmaxf(acc.y + bv.y, 0.f);
    op[2] = fmaxf(acc.z + bv.z, 0.f);
    op[3] = fmaxf(acc.w + bv.w, 0.f);
}

// ---------------------------------------------------------------------------
// Attention: grid (L/8, B*H), 256 threads. Scores for 8 q-rows in LDS,
// two-phase softmax (mask is all-False since every graph has exactly L nodes).
// qkv layout: [B*L, 768] with q|k|v concatenated, head-major channels.
// ---------------------------------------------------------------------------
__global__ __launch_bounds__(256) void attn_kernel(
    const float* __restrict__ qkv, float* __restrict__ out)
{
    __shared__ float qs[8][32];
    __shared__ float sc[8][1024];
    __shared__ float lsums[8];
    int t = threadIdx.x;
    int bh = blockIdx.y;
    int b = bh >> 3, h = bh & 7;
    int q0 = blockIdx.x * 8;
    const float scale = 0.17677669529663687f;   // 1/sqrt(32)
    {
        int r = t >> 5, c = t & 31;
        qs[r][c] = qkv[(size_t)(b * LL + q0 + r) * 768 + h * 32 + c] * scale;
    }
    __syncthreads();
    const float* kbase = qkv + (size_t)b * LL * 768 + 256 + h * 32;
#pragma unroll 4
    for (int i = 0; i < 32; ++i) {
        int idx = i * 256 + t;
        int j = idx >> 3, r = idx & 7;
        const float* krow = kbase + (size_t)j * 768;
        float s = 0.f;
#pragma unroll
        for (int c = 0; c < 32; ++c) s += qs[r][c] * krow[c];
        sc[r][j] = s;
    }
    __syncthreads();
    {
        int r = t >> 5, lane = t & 31;
        float mmax = -1e30f;
        for (int j = lane; j < 1024; j += 32) mmax = fmaxf(mmax, sc[r][j]);
#pragma unroll
        for (int off = 16; off; off >>= 1) mmax = fmaxf(mmax, __shfl_xor(mmax, off));
        float lsum = 0.f;
        for (int j = lane; j < 1024; j += 32) {
            float p = __expf(sc[r][j] - mmax);
            sc[r][j] = p;
            lsum += p;
        }
#pragma unroll
        for (int off = 16; off; off >>= 1) lsum += __shfl_xor(lsum, off);
        if (lane == 0) lsums[r] = lsum;
    }
    __syncthreads();
    {
        int c = t & 31, r = t >> 5;
        const float* vbase = qkv + (size_t)b * LL * 768 + 512 + h * 32 + c;
        float acc = 0.f;
        for (int j = 0; j < 1024; ++j) acc += sc[r][j] * vbase[(size_t)j * 768];
        out[(size_t)(b * LL + q0 + r) * DD + h * 32 + c] = acc / lsums[r];
    }
}

// ---------------------------------------------------------------------------
// LayerNorm over rows of 256, in place: one wave per row.
// ---------------------------------------------------------------------------
__global__ __launch_bounds__(256) void ln_kernel(
    float* __restrict__ x, const float* __restrict__ w, const float* __restrict__ b)
{
    int wid = threadIdx.x >> 6, lane = threadIdx.x & 63;
    size_t row = blockIdx.x * 4 + wid;
    float4 v = *(float4*)(x + row * DD + lane * 4);
    float s = v.x + v.y + v.z + v.w;
#pragma unroll
    for (int off = 32; off; off >>= 1) s += __shfl_xor(s, off);
    float mu = s * (1.f / 256.f);
    float dx = v.x - mu, dy = v.y - mu, dz = v.z - mu, dw = v.w - mu;
    float q = dx * dx + dy * dy + dz * dz + dw * dw;
#pragma unroll
    for (int off = 32; off; off >>= 1) q += __shfl_xor(q, off);
    float rstd = rsqrtf(q * (1.f / 256.f) + 1e-5f);
    int c = lane * 4;
    float4 wv = *(const float4*)(w + c);
    float4 bv = *(const float4*)(b + c);
    float4 o;
    o.x = dx * rstd * wv.x + bv.x;
    o.y = dy * rstd * wv.y + bv.y;
    o.z = dz * rstd * wv.z + bv.z;
    o.w = dw * rstd * wv.w + bv.w;
    *(float4*)(x + row * DD + c) = o;
}

// ---------------------------------------------------------------------------
// Final prediction head: out[m,o] = x[m,:] . pred_w[o,:] + pred_b[o]
// ---------------------------------------------------------------------------
__global__ __launch_bounds__(256) void pred_kernel(
    const float* __restrict__ x, const float* __restrict__ w,
    const float* __restrict__ b, float* __restrict__ out)
{
    int idx = blockIdx.x * 256 + threadIdx.x;   // 24576
    int m = idx / 3, o = idx % 3;
    const float* xr = x + (size_t)m * DD;
    const float* wr = w + o * DD;
    float s = b[o];
#pragma unroll 8
    for (int c = 0; c < DD; ++c) s += xr[c] * wr[c];
    out[idx] = s;
}

// ---------------------------------------------------------------------------
extern "C" void kernel_launch(void* const* d_in, const int* in_sizes, int n_in,
                              void* d_out, int out_size, void* d_ws, size_t ws_size,
                              hipStream_t stream)
{
    const float* x        = (const float*)d_in[0];
    const int*   ei       = (const int*)d_in[1];
    const float* gat_W0   = (const float*)d_in[3];
    const float* gat_W12  = (const float*)d_in[4];
    const float* att_src  = (const float*)d_in[5];
    const float* att_dst  = (const float*)d_in[6];
    const float* gat_bias = (const float*)d_in[7];
    const float* qkv_w    = (const float*)d_in[8];
    const float* qkv_b    = (const float*)d_in[9];
    const float* out_w    = (const float*)d_in[10];
    const float* out_b    = (const float*)d_in[11];
    const float* ln1_w    = (const float*)d_in[12];
    const float* ln1_b    = (const float*)d_in[13];
    const float* ln2_w    = (const float*)d_in[14];
    const float* ln2_b    = (const float*)d_in[15];
    const float* ff1_w    = (const float*)d_in[16];
    const float* ff1_b    = (const float*)d_in[17];
    const float* ff2_w    = (const float*)d_in[18];
    const float* ff2_b    = (const float*)d_in[19];
    const float* pred_w   = (const float*)d_in[20];
    const float* pred_b   = (const float*)d_in[21];
    float* outp = (float*)d_out;

    // workspace layout (floats)
    float* ws      = (float*)d_ws;
    float* hA      = ws;                               // 2M floats
    float* hB      = ws + 2097152;                     // 2M floats
    float* R0      = ws + 4194304;                     // 16M floats shared region
    float* qkvbuf  = R0;                               // 6M floats
    float* attnbuf = R0 + 8388608;                     // 2M floats
    float* ffbuf   = R0;                               // 16M floats (after attn consumed)
    float* a_s     = ws + 20971520;                    // 64K floats
    float* a_d     = a_s + 65536;
    int*   iw      = (int*)(a_d + 65536);
    int*   deg     = iw;
    int*   rowptr  = iw + 8192;                        // 8193 ints
    int*   cursor  = iw + 16392;
    int*   col     = iw + 24592;                       // 270336 ints

    // ---- CSR build (every launch: ws is poisoned) ----
    hipMemsetAsync(deg, 0, NN * sizeof(int), stream);
    int etot = EE + NN;
    count_kernel<<<(etot + 255) / 256, 256, 0, stream>>>(ei, deg);
    scan_kernel<<<1, 1024, 0, stream>>>(deg, rowptr, cursor);
    scatter_kernel<<<(etot + 255) / 256, 256, 0, stream>>>(ei, cursor, col);

    // ---- GAT layer 0 ----
    gemm_kernel<false, false, false><<<dim3(128, 4), 256, 0, stream>>>(
        x, gat_W0, nullptr, nullptr, hA, NN, DD, 64);
    asd_kernel<<<256, 256, 0, stream>>>(hA, att_src, att_dst, a_s, a_d);
    gat_agg_kernel<<<2048, 256, 0, stream>>>(hA, a_s, a_d, rowptr, col, gat_bias, hB);

    // ---- GAT layers 1,2 ----
    for (int l = 0; l < 2; ++l) {
        gemm_kernel<false, false, false><<<dim3(128, 4), 256, 0, stream>>>(
            hB, gat_W12 + (size_t)l * DD * DD, nullptr, nullptr, hA, NN, DD, DD);
        asd_kernel<<<256, 256, 0, stream>>>(
            hA, att_src + (l + 1) * 256, att_dst + (l + 1) * 256, a_s, a_d);
        gat_agg_kernel<<<2048, 256, 0, stream>>>(
            hA, a_s, a_d, rowptr, col, gat_bias + (l + 1) * 256, hB);
    }

    // ---- Transformer layers (x lives in hB at loop top and bottom) ----
    for (int l = 0; l < 2; ++l) {
        gemm_kernel<true, false, false><<<dim3(128, 12), 256, 0, stream>>>(
            hB, qkv_w + (size_t)l * 768 * DD, qkv_b + l * 768, nullptr,
            qkvbuf, NN, 768, DD);
        attn_kernel<<<dim3(128, 64), 256, 0, stream>>>(qkvbuf, attnbuf);
        gemm_kernel<true, false, true><<<dim3(128, 4), 256, 0, stream>>>(
            attnbuf, out_w + (size_t)l * DD * DD, out_b + l * DD, hB, hA, NN, DD, DD);
        ln_kernel<<<2048, 256, 0, stream>>>(hA, ln1_w + l * DD, ln1_b + l * DD);
        gemm_kernel<true, true, false><<<dim3(128, 32), 256, 0, stream>>>(
            hA, ff1_w + (size_t)l * DFFN * DD, ff1_b + l * DFFN, nullptr,
            ffbuf, NN, DFFN, DD);
        gemm_kernel<true, false, true><<<dim3(128, 4), 256, 0, stream>>>(
            ffbuf, ff2_w + (size_t)l * DD * DFFN, ff2_b + l * DD, hA, hB, NN, DD, DFFN);
        ln_kernel<<<2048, 256, 0, stream>>>(hB, ln2_w + l * DD, ln2_b + l * DD);
    }

    // ---- prediction head ----
    pred_kernel<<<96, 256, 0, stream>>>(hB, pred_w, pred_b, outp);
}

// Round 2
// 1381.055 us; speedup vs baseline: 1.5904x; 1.5904x over previous
//
#include <hip/hip_runtime.h>
#include <hip/hip_bf16.h>

#define NN 8192
#define EE 262144
#define BB 8
#define LL 1024
#define HH 8
#define DD 256
#define DFFN 2048

typedef short s8v __attribute__((ext_vector_type(8)));
typedef float f32x4 __attribute__((ext_vector_type(4)));

__device__ inline unsigned short f2bf(float f) {
    unsigned u = __float_as_uint(f);
    u = (u + 0x7fffu + ((u >> 16) & 1u)) >> 16;
    return (unsigned short)u;
}

// ---------------------------------------------------------------------------
// Generic tiled fp32 GEMM: C[M,N] = A[M,K] @ W[N,K]^T (+bias) (+res) (relu?)
// 64x64 tile, BK=16, 256 threads, 4x4 per thread.
// ---------------------------------------------------------------------------
template<bool BIAS, bool RELU, bool RES>
__global__ __launch_bounds__(256) void gemm_kernel(
    const float* __restrict__ A, const float* __restrict__ W,
    const float* __restrict__ bias, const float* __restrict__ res,
    float* __restrict__ C, int M, int N, int K)
{
    __shared__ float As[16][65];
    __shared__ float Bs[16][65];
    int t  = threadIdx.x;
    int m0 = blockIdx.x * 64;
    int n0 = blockIdx.y * 64;
    int lr = t >> 2;          // 0..63
    int lk = (t & 3) * 4;     // 0,4,8,12
    int ty = t >> 4, tx = t & 15;
    float acc[4][4] = {};
    for (int k0 = 0; k0 < K; k0 += 16) {
        float4 av = *(const float4*)(A + (size_t)(m0 + lr) * K + k0 + lk);
        float4 bv = *(const float4*)(W + (size_t)(n0 + lr) * K + k0 + lk);
        As[lk + 0][lr] = av.x; As[lk + 1][lr] = av.y;
        As[lk + 2][lr] = av.z; As[lk + 3][lr] = av.w;
        Bs[lk + 0][lr] = bv.x; Bs[lk + 1][lr] = bv.y;
        Bs[lk + 2][lr] = bv.z; Bs[lk + 3][lr] = bv.w;
        __syncthreads();
#pragma unroll
        for (int kk = 0; kk < 16; ++kk) {
            float a[4], b[4];
#pragma unroll
            for (int i = 0; i < 4; ++i) a[i] = As[kk][ty * 4 + i];
#pragma unroll
            for (int j = 0; j < 4; ++j) b[j] = Bs[kk][tx * 4 + j];
#pragma unroll
            for (int i = 0; i < 4; ++i)
#pragma unroll
                for (int j = 0; j < 4; ++j)
                    acc[i][j] += a[i] * b[j];
        }
        __syncthreads();
    }
#pragma unroll
    for (int i = 0; i < 4; ++i) {
        int m = m0 + ty * 4 + i;
#pragma unroll
        for (int j = 0; j < 4; ++j) {
            int n = n0 + tx * 4 + j;
            float v = acc[i][j];
            if (BIAS) v += bias[n];
            if (RES)  v += res[(size_t)m * N + n];
            if (RELU) v = fmaxf(v, 0.f);
            C[(size_t)m * N + n] = v;
        }
    }
}

// ---------------------------------------------------------------------------
// GAT: per-(node,head) attention logits a_s, a_d
// ---------------------------------------------------------------------------
__global__ __launch_bounds__(256) void asd_kernel(
    const float* __restrict__ h, const float* __restrict__ atts,
    const float* __restrict__ attd, float* __restrict__ a_s, float* __restrict__ a_d)
{
    int idx = blockIdx.x * 256 + threadIdx.x;   // n*8 + head, 65536 total
    int n = idx >> 3, hh = idx & 7;
    const float* hr = h + (size_t)n * DD + hh * 32;
    const float* sr = atts + hh * 32;
    const float* dr = attd + hh * 32;
    float ss = 0.f, sd = 0.f;
#pragma unroll
    for (int c = 0; c < 32; ++c) { float v = hr[c]; ss += v * sr[c]; sd += v * dr[c]; }
    a_s[idx] = ss; a_d[idx] = sd;
}

// ---------------------------------------------------------------------------
// CSR build (edges + self loops), rebuilt every launch (ws is poisoned)
// ---------------------------------------------------------------------------
__global__ void count_kernel(const int* __restrict__ ei, int* __restrict__ deg)
{
    int e = blockIdx.x * 256 + threadIdx.x;
    if (e >= EE + NN) return;
    int d = (e < EE) ? ei[EE + e] : (e - EE);
    atomicAdd(&deg[d], 1);
}

__global__ __launch_bounds__(1024) void scan_kernel(
    const int* __restrict__ deg, int* __restrict__ rowptr, int* __restrict__ cursor)
{
    __shared__ int part[1024];
    int t = threadIdx.x;
    int base = t * 8;
    int loc[8]; int s = 0;
#pragma unroll
    for (int i = 0; i < 8; ++i) { loc[i] = deg[base + i]; s += loc[i]; }
    part[t] = s;
    __syncthreads();
    for (int off = 1; off < 1024; off <<= 1) {
        int v = (t >= off) ? part[t - off] : 0;
        __syncthreads();
        part[t] += v;
        __syncthreads();
    }
    int run = (t == 0) ? 0 : part[t - 1];
#pragma unroll
    for (int i = 0; i < 8; ++i) { rowptr[base + i] = run; cursor[base + i] = run; run += loc[i]; }
    if (t == 1023) rowptr[NN] = run;
}

__global__ void scatter_kernel(const int* __restrict__ ei, int* __restrict__ cursor,
                               int* __restrict__ col)
{
    int e = blockIdx.x * 256 + threadIdx.x;
    if (e >= EE + NN) return;
    int s, d;
    if (e < EE) { s = ei[e]; d = ei[EE + e]; } else { s = e - EE; d = s; }
    int slot = atomicAdd(&cursor[d], 1);
    col[slot] = s;
}

// ---------------------------------------------------------------------------
// GAT aggregation: one 64-lane wave per dst node.
// ---------------------------------------------------------------------------
__global__ __launch_bounds__(256) void gat_agg_kernel(
    const float* __restrict__ hlin, const float* __restrict__ a_s,
    const float* __restrict__ a_d, const int* __restrict__ rowptr,
    const int* __restrict__ col, const float* __restrict__ bias,
    float* __restrict__ out)
{
    int wid = threadIdx.x >> 6, lane = threadIdx.x & 63;
    int dst = blockIdx.x * 4 + wid;
    int start = rowptr[dst], end = rowptr[dst + 1];
    float ad[HH];
#pragma unroll
    for (int h = 0; h < HH; ++h) ad[h] = a_d[(size_t)dst * HH + h];

    float m[HH];
#pragma unroll
    for (int h = 0; h < HH; ++h) m[h] = -1e30f;
    for (int e = start + lane; e < end; e += 64) {
        int s = col[e];
#pragma unroll
        for (int h = 0; h < HH; ++h) {
            float v = a_s[(size_t)s * HH + h] + ad[h];
            v = v > 0.f ? v : 0.2f * v;
            m[h] = fmaxf(m[h], v);
        }
    }
#pragma unroll
    for (int h = 0; h < HH; ++h)
#pragma unroll
        for (int off = 32; off; off >>= 1) m[h] = fmaxf(m[h], __shfl_xor(m[h], off));

    float sm[HH];
#pragma unroll
    for (int h = 0; h < HH; ++h) sm[h] = 0.f;
    for (int e = start + lane; e < end; e += 64) {
        int s = col[e];
#pragma unroll
        for (int h = 0; h < HH; ++h) {
            float v = a_s[(size_t)s * HH + h] + ad[h];
            v = v > 0.f ? v : 0.2f * v;
            sm[h] += __expf(v - m[h]);
        }
    }
#pragma unroll
    for (int h = 0; h < HH; ++h)
#pragma unroll
        for (int off = 32; off; off >>= 1) sm[h] += __shfl_xor(sm[h], off);

    int myh = lane >> 3;
    float mh = m[myh], sh = sm[myh], adh = ad[myh];
    float4 acc = make_float4(0.f, 0.f, 0.f, 0.f);
    for (int e = start; e < end; ++e) {
        int s = col[e];
        float v = a_s[(size_t)s * HH + myh] + adh;
        v = v > 0.f ? v : 0.2f * v;
        float alpha = __expf(v - mh) / sh;
        float4 hv = *(const float4*)(hlin + (size_t)s * DD + lane * 4);
        acc.x += alpha * hv.x; acc.y += alpha * hv.y;
        acc.z += alpha * hv.z; acc.w += alpha * hv.w;
    }
    float4 bv = *(const float4*)(bias + lane * 4);
    float* op = out + (size_t)dst * DD + lane * 4;
    op[0] = fmaxf(acc.x + bv.x, 0.f);
    op[1] = fmaxf(acc.y + bv.y, 0.f);
    op[2] = fmaxf(acc.z + bv.z, 0.f);
    op[3] = fmaxf(acc.w + bv.w, 0.f);
}

// ---------------------------------------------------------------------------
// Cast fp32 qkv [N,768] -> head-blocked bf16: Qb/Kb [bh][1024][32] (Q scaled),
// Vt [bh][32][1024].
// ---------------------------------------------------------------------------
__global__ __launch_bounds__(256) void cast_qkv_kernel(
    const float* __restrict__ qkv, unsigned short* __restrict__ Qb,
    unsigned short* __restrict__ Kb, unsigned short* __restrict__ Vt)
{
    int idx = blockIdx.x * 256 + threadIdx.x;    // 8192*768
    int n = idx / 768, col = idx - n * 768;
    int sec = col >> 8, hc = col & 255;
    int h = hc >> 5, c = hc & 31;
    int b = n >> 10, l = n & 1023;
    int bh = b * 8 + h;
    float v = qkv[idx];
    if (sec == 0)      Qb[bh * 32768 + l * 32 + c] = f2bf(v * 0.17677669529663687f);
    else if (sec == 1) Kb[bh * 32768 + l * 32 + c] = f2bf(v);
    else               Vt[bh * 32768 + c * 1024 + l] = f2bf(v);
}

// ---------------------------------------------------------------------------
// Fused MFMA attention. Block = 4 waves = one (bh, 16-q-row tile).
// Wave w covers keys [w*256, w*256+256). No mask (all graphs are full).
// ---------------------------------------------------------------------------
__global__ __launch_bounds__(256) void attn_mfma_kernel(
    const unsigned short* __restrict__ Qb, const unsigned short* __restrict__ Kb,
    const unsigned short* __restrict__ Vt, float* __restrict__ out)
{
    __shared__ unsigned short pb[16][1032];   // P, A-operand layout source
    __shared__ float wred[4][16];
    __shared__ float tsum[16];
    __shared__ float of[4][16][33];

    int t = threadIdx.x;
    int w = t >> 6, lane = t & 63;
    int quad = lane >> 4, l15 = lane & 15;
    int bh = blockIdx.y;
    int q0 = blockIdx.x * 16;
    int b = bh >> 3, h = bh & 7;

    const unsigned short* qbase = Qb + (size_t)bh * 32768;
    const unsigned short* kbase = Kb + (size_t)bh * 32768;
    const unsigned short* vbase = Vt + (size_t)bh * 32768;

    // A-frag of Q: A[m=lane&15][k=quad*8+i]
    s8v aq = *(const s8v*)(qbase + (q0 + l15) * 32 + quad * 8);

    f32x4 z = {0.f, 0.f, 0.f, 0.f};
    f32x4 s[16];
#pragma unroll
    for (int tt = 0; tt < 16; ++tt) {
        int jt = w * 256 + tt * 16;
        s8v bk = *(const s8v*)(kbase + (jt + l15) * 32 + quad * 8);
        s[tt] = __builtin_amdgcn_mfma_f32_16x16x32_bf16(aq, bk, z, 0, 0, 0);
    }

    // --- row max over this wave's 256 cols (C layout: row=quad*4+r, col=l15)
    float mx[4] = {-1e30f, -1e30f, -1e30f, -1e30f};
#pragma unroll
    for (int tt = 0; tt < 16; ++tt)
#pragma unroll
        for (int r = 0; r < 4; ++r) mx[r] = fmaxf(mx[r], s[tt][r]);
#pragma unroll
    for (int r = 0; r < 4; ++r)
#pragma unroll
        for (int off = 1; off < 16; off <<= 1)
            mx[r] = fmaxf(mx[r], __shfl_xor(mx[r], off));
    if (l15 == 0)
#pragma unroll
        for (int r = 0; r < 4; ++r) wred[w][quad * 4 + r] = mx[r];
    __syncthreads();
    float M[4];
#pragma unroll
    for (int r = 0; r < 4; ++r) {
        int row = quad * 4 + r;
        M[r] = fmaxf(fmaxf(wred[0][row], wred[1][row]),
                     fmaxf(wred[2][row], wred[3][row]));
    }
    __syncthreads();   // wred reused for sums

    // --- exp, P->LDS (bf16), row sums
    float sm[4] = {0.f, 0.f, 0.f, 0.f};
#pragma unroll
    for (int tt = 0; tt < 16; ++tt) {
        int jc = w * 256 + tt * 16 + l15;
#pragma unroll
        for (int r = 0; r < 4; ++r) {
            float p = __expf(s[tt][r] - M[r]);
            sm[r] += p;
            pb[quad * 4 + r][jc] = f2bf(p);
        }
    }
#pragma unroll
    for (int r = 0; r < 4; ++r)
#pragma unroll
        for (int off = 1; off < 16; off <<= 1)
            sm[r] += __shfl_xor(sm[r], off);
    if (l15 == 0)
#pragma unroll
        for (int r = 0; r < 4; ++r) wred[w][quad * 4 + r] = sm[r];
    __syncthreads();   // pb + wred visible to all
    if (w == 0 && l15 == 0)
#pragma unroll
        for (int r = 0; r < 4; ++r) {
            int row = quad * 4 + r;
            tsum[row] = wred[0][row] + wred[1][row] + wred[2][row] + wred[3][row];
        }

    // --- PV: wave w contracts its own 256 keys; 2 MFMAs (d halves) per 32-key tile
    f32x4 o0 = z, o1 = z;
#pragma unroll
    for (int k = 0; k < 8; ++k) {
        int j0 = w * 256 + k * 32;
        s8v ap = *(const s8v*)(&pb[l15][j0 + quad * 8]);
        s8v b0 = *(const s8v*)(vbase + (size_t)l15 * 1024 + j0 + quad * 8);
        s8v b1 = *(const s8v*)(vbase + (size_t)(16 + l15) * 1024 + j0 + quad * 8);
        o0 = __builtin_amdgcn_mfma_f32_16x16x32_bf16(ap, b0, o0, 0, 0, 0);
        o1 = __builtin_amdgcn_mfma_f32_16x16x32_bf16(ap, b1, o1, 0, 0, 0);
    }
#pragma unroll
    for (int r = 0; r < 4; ++r) {
        of[w][quad * 4 + r][l15]      = o0[r];
        of[w][quad * 4 + r][16 + l15] = o1[r];
    }
    __syncthreads();
    for (int i = t; i < 512; i += 256) {
        int row = i >> 5, col = i & 31;
        float v = (of[0][row][col] + of[1][row][col] +
                   of[2][row][col] + of[3][row][col]) / tsum[row];
        out[(size_t)(b * 1024 + q0 + row) * 256 + h * 32 + col] = v;
    }
}

// ---------------------------------------------------------------------------
// LayerNorm over rows of 256, in place: one wave per row.
// ---------------------------------------------------------------------------
__global__ __launch_bounds__(256) void ln_kernel(
    float* __restrict__ x, const float* __restrict__ w, const float* __restrict__ b)
{
    int wid = threadIdx.x >> 6, lane = threadIdx.x & 63;
    size_t row = blockIdx.x * 4 + wid;
    float4 v = *(float4*)(x + row * DD + lane * 4);
    float s = v.x + v.y + v.z + v.w;
#pragma unroll
    for (int off = 32; off; off >>= 1) s += __shfl_xor(s, off);
    float mu = s * (1.f / 256.f);
    float dx = v.x - mu, dy = v.y - mu, dz = v.z - mu, dw = v.w - mu;
    float q = dx * dx + dy * dy + dz * dz + dw * dw;
#pragma unroll
    for (int off = 32; off; off >>= 1) q += __shfl_xor(q, off);
    float rstd = rsqrtf(q * (1.f / 256.f) + 1e-5f);
    int c = lane * 4;
    float4 wv = *(const float4*)(w + c);
    float4 bv = *(const float4*)(b + c);
    float4 o;
    o.x = dx * rstd * wv.x + bv.x;
    o.y = dy * rstd * wv.y + bv.y;
    o.z = dz * rstd * wv.z + bv.z;
    o.w = dw * rstd * wv.w + bv.w;
    *(float4*)(x + row * DD + c) = o;
}

// ---------------------------------------------------------------------------
// Final prediction head
// ---------------------------------------------------------------------------
__global__ __launch_bounds__(256) void pred_kernel(
    const float* __restrict__ x, const float* __restrict__ w,
    const float* __restrict__ b, float* __restrict__ out)
{
    int idx = blockIdx.x * 256 + threadIdx.x;   // 24576
    int m = idx / 3, o = idx % 3;
    const float* xr = x + (size_t)m * DD;
    const float* wr = w + o * DD;
    float s = b[o];
#pragma unroll 8
    for (int c = 0; c < DD; ++c) s += xr[c] * wr[c];
    out[idx] = s;
}

// ---------------------------------------------------------------------------
extern "C" void kernel_launch(void* const* d_in, const int* in_sizes, int n_in,
                              void* d_out, int out_size, void* d_ws, size_t ws_size,
                              hipStream_t stream)
{
    const float* x        = (const float*)d_in[0];
    const int*   ei       = (const int*)d_in[1];
    const float* gat_W0   = (const float*)d_in[3];
    const float* gat_W12  = (const float*)d_in[4];
    const float* att_src  = (const float*)d_in[5];
    const float* att_dst  = (const float*)d_in[6];
    const float* gat_bias = (const float*)d_in[7];
    const float* qkv_w    = (const float*)d_in[8];
    const float* qkv_b    = (const float*)d_in[9];
    const float* out_w    = (const float*)d_in[10];
    const float* out_b    = (const float*)d_in[11];
    const float* ln1_w    = (const float*)d_in[12];
    const float* ln1_b    = (const float*)d_in[13];
    const float* ln2_w    = (const float*)d_in[14];
    const float* ln2_b    = (const float*)d_in[15];
    const float* ff1_w    = (const float*)d_in[16];
    const float* ff1_b    = (const float*)d_in[17];
    const float* ff2_w    = (const float*)d_in[18];
    const float* ff2_b    = (const float*)d_in[19];
    const float* pred_w   = (const float*)d_in[20];
    const float* pred_b   = (const float*)d_in[21];
    float* outp = (float*)d_out;

    // workspace layout (floats)
    float* ws      = (float*)d_ws;
    float* hA      = ws;                               // 2M floats
    float* hB      = ws + 2097152;                     // 2M floats
    float* R0      = ws + 4194304;                     // 16M floats shared region
    float* qkvbuf  = R0;                               // 6M floats
    unsigned short* Qb = (unsigned short*)(R0 + 6291456);   // 2M bf16
    unsigned short* Kb = Qb + 2097152;                      // 2M bf16
    unsigned short* Vt = Kb + 2097152;                      // 2M bf16
    float* attnbuf = R0 + 9437184;                     // 2M floats
    float* ffbuf   = R0;                               // 16M floats (attn consumed)
    float* a_s     = ws + 20971520;                    // 64K floats
    float* a_d     = a_s + 65536;
    int*   iw      = (int*)(a_d + 65536);
    int*   deg     = iw;
    int*   rowptr  = iw + 8192;                        // 8193 ints
    int*   cursor  = iw + 16392;
    int*   col     = iw + 24592;                       // 270336 ints

    // ---- CSR build (every launch: ws is poisoned) ----
    hipMemsetAsync(deg, 0, NN * sizeof(int), stream);
    int etot = EE + NN;
    count_kernel<<<(etot + 255) / 256, 256, 0, stream>>>(ei, deg);
    scan_kernel<<<1, 1024, 0, stream>>>(deg, rowptr, cursor);
    scatter_kernel<<<(etot + 255) / 256, 256, 0, stream>>>(ei, cursor, col);

    // ---- GAT layer 0 ----
    gemm_kernel<false, false, false><<<dim3(128, 4), 256, 0, stream>>>(
        x, gat_W0, nullptr, nullptr, hA, NN, DD, 64);
    asd_kernel<<<256, 256, 0, stream>>>(hA, att_src, att_dst, a_s, a_d);
    gat_agg_kernel<<<2048, 256, 0, stream>>>(hA, a_s, a_d, rowptr, col, gat_bias, hB);

    // ---- GAT layers 1,2 ----
    for (int l = 0; l < 2; ++l) {
        gemm_kernel<false, false, false><<<dim3(128, 4), 256, 0, stream>>>(
            hB, gat_W12 + (size_t)l * DD * DD, nullptr, nullptr, hA, NN, DD, DD);
        asd_kernel<<<256, 256, 0, stream>>>(
            hA, att_src + (l + 1) * 256, att_dst + (l + 1) * 256, a_s, a_d);
        gat_agg_kernel<<<2048, 256, 0, stream>>>(
            hA, a_s, a_d, rowptr, col, gat_bias + (l + 1) * 256, hB);
    }

    // ---- Transformer layers ----
    for (int l = 0; l < 2; ++l) {
        gemm_kernel<true, false, false><<<dim3(128, 12), 256, 0, stream>>>(
            hB, qkv_w + (size_t)l * 768 * DD, qkv_b + l * 768, nullptr,
            qkvbuf, NN, 768, DD);
        cast_qkv_kernel<<<24576, 256, 0, stream>>>(qkvbuf, Qb, Kb, Vt);
        attn_mfma_kernel<<<dim3(64, 64), 256, 0, stream>>>(Qb, Kb, Vt, attnbuf);
        gemm_kernel<true, false, true><<<dim3(128, 4), 256, 0, stream>>>(
            attnbuf, out_w + (size_t)l * DD * DD, out_b + l * DD, hB, hA, NN, DD, DD);
        ln_kernel<<<2048, 256, 0, stream>>>(hA, ln1_w + l * DD, ln1_b + l * DD);
        gemm_kernel<true, true, false><<<dim3(128, 32), 256, 0, stream>>>(
            hA, ff1_w + (size_t)l * DFFN * DD, ff1_b + l * DFFN, nullptr,
            ffbuf, NN, DFFN, DD);
        gemm_kernel<true, false, true><<<dim3(128, 4), 256, 0, stream>>>(
            ffbuf, ff2_w + (size_t)l * DD * DFFN, ff2_b + l * DD, hA, hB, NN, DD, DFFN);
        ln_kernel<<<2048, 256, 0, stream>>>(hB, ln2_w + l * DD, ln2_b + l * DD);
    }

    // ---- prediction head ----
    pred_kernel<<<96, 256, 0, stream>>>(hB, pred_w, pred_b, outp);
}

// Round 3
// 645.750 us; speedup vs baseline: 3.4013x; 2.1387x over previous
//
#include <hip/hip_runtime.h>
#include <hip/hip_bf16.h>

#define NN 8192
#define EE 262144
#define BB 8
#define LL 1024
#define HH 8
#define DD 256
#define DFFN 2048

typedef short s8v __attribute__((ext_vector_type(8)));
typedef float f32x4 __attribute__((ext_vector_type(4)));
typedef unsigned short ushort;

__device__ inline ushort f2bf(float f) {
    unsigned u = __float_as_uint(f);
    u = (u + 0x7fffu + ((u >> 16) & 1u)) >> 16;
    return (ushort)u;
}
__device__ inline float bf2f(ushort u) {
    return __uint_as_float(((unsigned)u) << 16);
}

// ---------------------------------------------------------------------------
// bf16 MFMA GEMM (m97 structure): C[M,N] = A[M,K] @ W[N,K]^T
// 128x128 tile, BK=32, 256 thr, global_load_lds(16B) staging, 4x4 frags/wave.
// Epilogue: optional bias, relu, fp32 residual; writes fp32 Cf and/or bf16 Cb.
// ---------------------------------------------------------------------------
template<bool BIAS, bool RELU, bool RES, bool WF, bool WB>
__global__ __launch_bounds__(256) void mgemm_kernel(
    const ushort* __restrict__ A, const ushort* __restrict__ W,
    const float* __restrict__ bias, const float* __restrict__ res,
    float* __restrict__ Cf, ushort* __restrict__ Cb, int M, int N, int K)
{
    __shared__ ushort As[128 * 32];
    __shared__ ushort Bs[128 * 32];
    int t = threadIdx.x;
    int l = t & 63;
    int quad = l >> 4, l15 = l & 15;
    int w = t >> 6;
    int wm = (w >> 1) * 64, wn = (w & 1) * 64;
    int m0 = blockIdx.x * 128, n0 = blockIdx.y * 128;

    f32x4 z = {0.f, 0.f, 0.f, 0.f};
    f32x4 acc[4][4];
#pragma unroll
    for (int i = 0; i < 4; ++i)
#pragma unroll
        for (int j = 0; j < 4; ++j) acc[i][j] = z;

    for (int k0 = 0; k0 < K; k0 += 32) {
#pragma unroll
        for (int i = 0; i < 2; ++i) {
            int chunk = i * 256 + t;      // 16B chunk id
            int e = chunk * 8;            // element offset in tile
            int r = e >> 5, c = e & 31;
            __builtin_amdgcn_global_load_lds(
                (const __attribute__((address_space(1))) unsigned int*)
                    (A + (size_t)(m0 + r) * K + k0 + c),
                (__attribute__((address_space(3))) unsigned int*)(As + e), 16, 0, 0);
            __builtin_amdgcn_global_load_lds(
                (const __attribute__((address_space(1))) unsigned int*)
                    (W + (size_t)(n0 + r) * K + k0 + c),
                (__attribute__((address_space(3))) unsigned int*)(Bs + e), 16, 0, 0);
        }
        __syncthreads();
        s8v af[4], bfv[4];
#pragma unroll
        for (int i = 0; i < 4; ++i) {
            af[i]  = *(const s8v*)(As + (wm + i * 16 + l15) * 32 + quad * 8);
            bfv[i] = *(const s8v*)(Bs + (wn + i * 16 + l15) * 32 + quad * 8);
        }
#pragma unroll
        for (int mi = 0; mi < 4; ++mi)
#pragma unroll
            for (int ni = 0; ni < 4; ++ni)
                acc[mi][ni] = __builtin_amdgcn_mfma_f32_16x16x32_bf16(
                    af[mi], bfv[ni], acc[mi][ni], 0, 0, 0);
        __syncthreads();
    }

#pragma unroll
    for (int mi = 0; mi < 4; ++mi) {
#pragma unroll
        for (int ni = 0; ni < 4; ++ni) {
            int n = n0 + wn + ni * 16 + l15;
#pragma unroll
            for (int r = 0; r < 4; ++r) {
                int m = m0 + wm + mi * 16 + quad * 4 + r;
                float v = acc[mi][ni][r];
                if (BIAS) v += bias[n];
                if (RES)  v += res[(size_t)m * N + n];
                if (RELU) v = fmaxf(v, 0.f);
                if (WF) Cf[(size_t)m * N + n] = v;
                if (WB) Cb[(size_t)m * N + n] = f2bf(v);
            }
        }
    }
}

// ---------------------------------------------------------------------------
// Weight casts fp32 -> bf16 (rebuilt every launch; ws is poisoned)
// ---------------------------------------------------------------------------
__global__ __launch_bounds__(256) void castw_kernel(
    const float* __restrict__ W0, const float* __restrict__ W12,
    const float* __restrict__ qkvw, const float* __restrict__ outw,
    const float* __restrict__ f1w, const float* __restrict__ f2w,
    ushort* __restrict__ W0b, ushort* __restrict__ W12b,
    ushort* __restrict__ qkvb, ushort* __restrict__ outb,
    ushort* __restrict__ f1b, ushort* __restrict__ f2b)
{
    int e = (blockIdx.x * 256 + threadIdx.x) * 4;   // 2,768,896 total elems
    if (e >= 2768896) return;
    const float* s; ushort* d; int off;
    if (e < 16384)        { s = W0;   d = W0b;  off = e; }
    else if (e < 147456)  { s = W12;  d = W12b; off = e - 16384; }
    else if (e < 540672)  { s = qkvw; d = qkvb; off = e - 147456; }
    else if (e < 671744)  { s = outw; d = outb; off = e - 540672; }
    else if (e < 1720320) { s = f1w;  d = f1b;  off = e - 671744; }
    else                  { s = f2w;  d = f2b;  off = e - 1720320; }
    float4 v = *(const float4*)(s + off);
    d[off + 0] = f2bf(v.x); d[off + 1] = f2bf(v.y);
    d[off + 2] = f2bf(v.z); d[off + 3] = f2bf(v.w);
}

__global__ __launch_bounds__(256) void castf_kernel(
    const float* __restrict__ s, ushort* __restrict__ d, int n4)
{
    int i = blockIdx.x * 256 + threadIdx.x;
    if (i >= n4) return;
    float4 v = *(const float4*)(s + i * 4);
    d[i * 4 + 0] = f2bf(v.x); d[i * 4 + 1] = f2bf(v.y);
    d[i * 4 + 2] = f2bf(v.z); d[i * 4 + 3] = f2bf(v.w);
}

// ---------------------------------------------------------------------------
// GAT: per-(node,head) attention logits a_s, a_d
// ---------------------------------------------------------------------------
__global__ __launch_bounds__(256) void asd_kernel(
    const float* __restrict__ h, const float* __restrict__ atts,
    const float* __restrict__ attd, float* __restrict__ a_s, float* __restrict__ a_d)
{
    int idx = blockIdx.x * 256 + threadIdx.x;   // n*8 + head
    int n = idx >> 3, hh = idx & 7;
    const float* hr = h + (size_t)n * DD + hh * 32;
    const float* sr = atts + hh * 32;
    const float* dr = attd + hh * 32;
    float ss = 0.f, sd = 0.f;
#pragma unroll
    for (int c = 0; c < 32; ++c) { float v = hr[c]; ss += v * sr[c]; sd += v * dr[c]; }
    a_s[idx] = ss; a_d[idx] = sd;
}

// ---------------------------------------------------------------------------
// CSR build
// ---------------------------------------------------------------------------
__global__ void count_kernel(const int* __restrict__ ei, int* __restrict__ deg)
{
    int e = blockIdx.x * 256 + threadIdx.x;
    if (e >= EE + NN) return;
    int d = (e < EE) ? ei[EE + e] : (e - EE);
    atomicAdd(&deg[d], 1);
}

__global__ __launch_bounds__(1024) void scan_kernel(
    const int* __restrict__ deg, int* __restrict__ rowptr, int* __restrict__ cursor)
{
    __shared__ int part[1024];
    int t = threadIdx.x;
    int base = t * 8;
    int loc[8]; int s = 0;
#pragma unroll
    for (int i = 0; i < 8; ++i) { loc[i] = deg[base + i]; s += loc[i]; }
    part[t] = s;
    __syncthreads();
    for (int off = 1; off < 1024; off <<= 1) {
        int v = (t >= off) ? part[t - off] : 0;
        __syncthreads();
        part[t] += v;
        __syncthreads();
    }
    int run = (t == 0) ? 0 : part[t - 1];
#pragma unroll
    for (int i = 0; i < 8; ++i) { rowptr[base + i] = run; cursor[base + i] = run; run += loc[i]; }
    if (t == 1023) rowptr[NN] = run;
}

__global__ void scatter_kernel(const int* __restrict__ ei, int* __restrict__ cursor,
                               int* __restrict__ col)
{
    int e = blockIdx.x * 256 + threadIdx.x;
    if (e >= EE + NN) return;
    int s, d;
    if (e < EE) { s = ei[e]; d = ei[EE + e]; } else { s = e - EE; d = s; }
    int slot = atomicAdd(&cursor[d], 1);
    col[slot] = s;
}

// ---------------------------------------------------------------------------
// GAT aggregation: one wave per dst node; dual fp32+bf16 output.
// ---------------------------------------------------------------------------
__global__ __launch_bounds__(256) void gat_agg_kernel(
    const float* __restrict__ hlin, const float* __restrict__ a_s,
    const float* __restrict__ a_d, const int* __restrict__ rowptr,
    const int* __restrict__ col, const float* __restrict__ bias,
    float* __restrict__ out, ushort* __restrict__ outb)
{
    int wid = threadIdx.x >> 6, lane = threadIdx.x & 63;
    int dst = blockIdx.x * 4 + wid;
    int start = rowptr[dst], end = rowptr[dst + 1];
    float ad[HH];
#pragma unroll
    for (int h = 0; h < HH; ++h) ad[h] = a_d[(size_t)dst * HH + h];

    float m[HH];
#pragma unroll
    for (int h = 0; h < HH; ++h) m[h] = -1e30f;
    for (int e = start + lane; e < end; e += 64) {
        int s = col[e];
#pragma unroll
        for (int h = 0; h < HH; ++h) {
            float v = a_s[(size_t)s * HH + h] + ad[h];
            v = v > 0.f ? v : 0.2f * v;
            m[h] = fmaxf(m[h], v);
        }
    }
#pragma unroll
    for (int h = 0; h < HH; ++h)
#pragma unroll
        for (int off = 32; off; off >>= 1) m[h] = fmaxf(m[h], __shfl_xor(m[h], off));

    float sm[HH];
#pragma unroll
    for (int h = 0; h < HH; ++h) sm[h] = 0.f;
    for (int e = start + lane; e < end; e += 64) {
        int s = col[e];
#pragma unroll
        for (int h = 0; h < HH; ++h) {
            float v = a_s[(size_t)s * HH + h] + ad[h];
            v = v > 0.f ? v : 0.2f * v;
            sm[h] += __expf(v - m[h]);
        }
    }
#pragma unroll
    for (int h = 0; h < HH; ++h)
#pragma unroll
        for (int off = 32; off; off >>= 1) sm[h] += __shfl_xor(sm[h], off);

    int myh = lane >> 3;
    float mh = m[myh], sh = sm[myh], adh = ad[myh];
    float4 acc = make_float4(0.f, 0.f, 0.f, 0.f);
    for (int e = start; e < end; ++e) {
        int s = col[e];
        float v = a_s[(size_t)s * HH + myh] + adh;
        v = v > 0.f ? v : 0.2f * v;
        float alpha = __expf(v - mh) / sh;
        float4 hv = *(const float4*)(hlin + (size_t)s * DD + lane * 4);
        acc.x += alpha * hv.x; acc.y += alpha * hv.y;
        acc.z += alpha * hv.z; acc.w += alpha * hv.w;
    }
    float4 bv = *(const float4*)(bias + lane * 4);
    float r0 = fmaxf(acc.x + bv.x, 0.f);
    float r1 = fmaxf(acc.y + bv.y, 0.f);
    float r2 = fmaxf(acc.z + bv.z, 0.f);
    float r3 = fmaxf(acc.w + bv.w, 0.f);
    float* op = out + (size_t)dst * DD + lane * 4;
    op[0] = r0; op[1] = r1; op[2] = r2; op[3] = r3;
    ushort* ob = outb + (size_t)dst * DD + lane * 4;
    ob[0] = f2bf(r0); ob[1] = f2bf(r1); ob[2] = f2bf(r2); ob[3] = f2bf(r3);
}

// ---------------------------------------------------------------------------
// Re-layout bf16 qkv [N,768] -> Qb/Kb [bh][1024][32] (Q scaled), Vt [bh][32][1024]
// ---------------------------------------------------------------------------
__global__ __launch_bounds__(256) void cast_qkv_kernel(
    const ushort* __restrict__ qkv, ushort* __restrict__ Qb,
    ushort* __restrict__ Kb, ushort* __restrict__ Vt)
{
    int idx = blockIdx.x * 256 + threadIdx.x;    // 8192*768
    int n = idx / 768, col = idx - n * 768;
    int sec = col >> 8, hc = col & 255;
    int h = hc >> 5, c = hc & 31;
    int b = n >> 10, l = n & 1023;
    int bh = b * 8 + h;
    ushort u = qkv[idx];
    if (sec == 0)      Qb[bh * 32768 + l * 32 + c] = f2bf(bf2f(u) * 0.17677669529663687f);
    else if (sec == 1) Kb[bh * 32768 + l * 32 + c] = u;
    else               Vt[bh * 32768 + c * 1024 + l] = u;
}

// ---------------------------------------------------------------------------
// Fused MFMA attention. Block = 4 waves = one (bh, 16-q-row tile).
// ---------------------------------------------------------------------------
__global__ __launch_bounds__(256) void attn_mfma_kernel(
    const ushort* __restrict__ Qb, const ushort* __restrict__ Kb,
    const ushort* __restrict__ Vt, ushort* __restrict__ outb)
{
    __shared__ ushort pb[16][1032];
    __shared__ float wred[4][16];
    __shared__ float tsum[16];
    __shared__ float of[4][16][33];

    int t = threadIdx.x;
    int w = t >> 6, lane = t & 63;
    int quad = lane >> 4, l15 = lane & 15;
    int bh = blockIdx.y;
    int q0 = blockIdx.x * 16;
    int b = bh >> 3, h = bh & 7;

    const ushort* qbase = Qb + (size_t)bh * 32768;
    const ushort* kbase = Kb + (size_t)bh * 32768;
    const ushort* vbase = Vt + (size_t)bh * 32768;

    s8v aq = *(const s8v*)(qbase + (q0 + l15) * 32 + quad * 8);

    f32x4 z = {0.f, 0.f, 0.f, 0.f};
    f32x4 s[16];
#pragma unroll
    for (int tt = 0; tt < 16; ++tt) {
        int jt = w * 256 + tt * 16;
        s8v bk = *(const s8v*)(kbase + (jt + l15) * 32 + quad * 8);
        s[tt] = __builtin_amdgcn_mfma_f32_16x16x32_bf16(aq, bk, z, 0, 0, 0);
    }

    float mx[4] = {-1e30f, -1e30f, -1e30f, -1e30f};
#pragma unroll
    for (int tt = 0; tt < 16; ++tt)
#pragma unroll
        for (int r = 0; r < 4; ++r) mx[r] = fmaxf(mx[r], s[tt][r]);
#pragma unroll
    for (int r = 0; r < 4; ++r)
#pragma unroll
        for (int off = 1; off < 16; off <<= 1)
            mx[r] = fmaxf(mx[r], __shfl_xor(mx[r], off));
    if (l15 == 0)
#pragma unroll
        for (int r = 0; r < 4; ++r) wred[w][quad * 4 + r] = mx[r];
    __syncthreads();
    float M[4];
#pragma unroll
    for (int r = 0; r < 4; ++r) {
        int row = quad * 4 + r;
        M[r] = fmaxf(fmaxf(wred[0][row], wred[1][row]),
                     fmaxf(wred[2][row], wred[3][row]));
    }
    __syncthreads();

    float sm[4] = {0.f, 0.f, 0.f, 0.f};
#pragma unroll
    for (int tt = 0; tt < 16; ++tt) {
        int jc = w * 256 + tt * 16 + l15;
#pragma unroll
        for (int r = 0; r < 4; ++r) {
            float p = __expf(s[tt][r] - M[r]);
            sm[r] += p;
            pb[quad * 4 + r][jc] = f2bf(p);
        }
    }
#pragma unroll
    for (int r = 0; r < 4; ++r)
#pragma unroll
        for (int off = 1; off < 16; off <<= 1)
            sm[r] += __shfl_xor(sm[r], off);
    if (l15 == 0)
#pragma unroll
        for (int r = 0; r < 4; ++r) wred[w][quad * 4 + r] = sm[r];
    __syncthreads();
    if (w == 0 && l15 == 0)
#pragma unroll
        for (int r = 0; r < 4; ++r) {
            int row = quad * 4 + r;
            tsum[row] = wred[0][row] + wred[1][row] + wred[2][row] + wred[3][row];
        }

    f32x4 o0 = z, o1 = z;
#pragma unroll
    for (int k = 0; k < 8; ++k) {
        int j0 = w * 256 + k * 32;
        s8v ap = *(const s8v*)(&pb[l15][j0 + quad * 8]);
        s8v b0 = *(const s8v*)(vbase + (size_t)l15 * 1024 + j0 + quad * 8);
        s8v b1 = *(const s8v*)(vbase + (size_t)(16 + l15) * 1024 + j0 + quad * 8);
        o0 = __builtin_amdgcn_mfma_f32_16x16x32_bf16(ap, b0, o0, 0, 0, 0);
        o1 = __builtin_amdgcn_mfma_f32_16x16x32_bf16(ap, b1, o1, 0, 0, 0);
    }
#pragma unroll
    for (int r = 0; r < 4; ++r) {
        of[w][quad * 4 + r][l15]      = o0[r];
        of[w][quad * 4 + r][16 + l15] = o1[r];
    }
    __syncthreads();
    for (int i = t; i < 512; i += 256) {
        int row = i >> 5, col = i & 31;
        float v = (of[0][row][col] + of[1][row][col] +
                   of[2][row][col] + of[3][row][col]) / tsum[row];
        outb[(size_t)(b * 1024 + q0 + row) * 256 + h * 32 + col] = f2bf(v);
    }
}

// ---------------------------------------------------------------------------
// LayerNorm in place (fp32) + bf16 copy out.
// ---------------------------------------------------------------------------
__global__ __launch_bounds__(256) void ln_kernel(
    float* __restrict__ x, const float* __restrict__ w, const float* __restrict__ b,
    ushort* __restrict__ xb)
{
    int wid = threadIdx.x >> 6, lane = threadIdx.x & 63;
    size_t row = blockIdx.x * 4 + wid;
    float4 v = *(float4*)(x + row * DD + lane * 4);
    float s = v.x + v.y + v.z + v.w;
#pragma unroll
    for (int off = 32; off; off >>= 1) s += __shfl_xor(s, off);
    float mu = s * (1.f / 256.f);
    float dx = v.x - mu, dy = v.y - mu, dz = v.z - mu, dw = v.w - mu;
    float q = dx * dx + dy * dy + dz * dz + dw * dw;
#pragma unroll
    for (int off = 32; off; off >>= 1) q += __shfl_xor(q, off);
    float rstd = rsqrtf(q * (1.f / 256.f) + 1e-5f);
    int c = lane * 4;
    float4 wv = *(const float4*)(w + c);
    float4 bv = *(const float4*)(b + c);
    float4 o;
    o.x = dx * rstd * wv.x + bv.x;
    o.y = dy * rstd * wv.y + bv.y;
    o.z = dz * rstd * wv.z + bv.z;
    o.w = dw * rstd * wv.w + bv.w;
    *(float4*)(x + row * DD + c) = o;
    ushort* ob = xb + row * DD + c;
    ob[0] = f2bf(o.x); ob[1] = f2bf(o.y); ob[2] = f2bf(o.z); ob[3] = f2bf(o.w);
}

// ---------------------------------------------------------------------------
// Final prediction head
// ---------------------------------------------------------------------------
__global__ __launch_bounds__(256) void pred_kernel(
    const float* __restrict__ x, const float* __restrict__ w,
    const float* __restrict__ b, float* __restrict__ out)
{
    int idx = blockIdx.x * 256 + threadIdx.x;   // 24576
    int m = idx / 3, o = idx % 3;
    const float* xr = x + (size_t)m * DD;
    const float* wr = w + o * DD;
    float s = b[o];
#pragma unroll 8
    for (int c = 0; c < DD; ++c) s += xr[c] * wr[c];
    out[idx] = s;
}

// ---------------------------------------------------------------------------
extern "C" void kernel_launch(void* const* d_in, const int* in_sizes, int n_in,
                              void* d_out, int out_size, void* d_ws, size_t ws_size,
                              hipStream_t stream)
{
    const float* x        = (const float*)d_in[0];
    const int*   ei       = (const int*)d_in[1];
    const float* gat_W0   = (const float*)d_in[3];
    const float* gat_W12  = (const float*)d_in[4];
    const float* att_src  = (const float*)d_in[5];
    const float* att_dst  = (const float*)d_in[6];
    const float* gat_bias = (const float*)d_in[7];
    const float* qkv_w    = (const float*)d_in[8];
    const float* qkv_b    = (const float*)d_in[9];
    const float* out_w    = (const float*)d_in[10];
    const float* out_b    = (const float*)d_in[11];
    const float* ln1_w    = (const float*)d_in[12];
    const float* ln1_b    = (const float*)d_in[13];
    const float* ln2_w    = (const float*)d_in[14];
    const float* ln2_b    = (const float*)d_in[15];
    const float* ff1_w    = (const float*)d_in[16];
    const float* ff1_b    = (const float*)d_in[17];
    const float* ff2_w    = (const float*)d_in[18];
    const float* ff2_b    = (const float*)d_in[19];
    const float* pred_w   = (const float*)d_in[20];
    const float* pred_b   = (const float*)d_in[21];
    float* outp = (float*)d_out;

    // workspace layout (float offsets)
    float* ws   = (float*)d_ws;
    float* hA   = ws;                                    // [8192,256] f32
    float* hB   = ws + 2097152;                          // [8192,256] f32
    ushort* ffb  = (ushort*)(ws + 4194304);              // [8192,2048] bf16 (region R)
    ushort* qb16 = (ushort*)(ws + 4194304);              // [8192,768] bf16 (alias, disjoint lifetime)
    ushort* Qb   = (ushort*)(ws + 12582912);             // [64][1024][32]
    ushort* Kb   = (ushort*)(ws + 13631488);
    ushort* Vt   = (ushort*)(ws + 14680064);             // [64][32][1024]
    ushort* attnb= (ushort*)(ws + 15728640);             // [8192,256] bf16
    ushort* lnb  = (ushort*)(ws + 16777216);             // [8192,256] bf16
    ushort* hBb  = (ushort*)(ws + 17825792);             // [8192,256] bf16
    ushort* xb   = (ushort*)(ws + 18874368);             // [8192,64] bf16
    ushort* wbase= (ushort*)(ws + 19136512);             // bf16 weights
    ushort* W0b    = wbase;                              // 16384
    ushort* W12b   = wbase + 16384;                      // 131072
    ushort* qkv_wb = wbase + 147456;                     // 393216
    ushort* out_wb = wbase + 540672;                     // 131072
    ushort* ff1_wb = wbase + 671744;                     // 1048576
    ushort* ff2_wb = wbase + 1720320;                    // 1048576
    float* a_s  = ws + 20520960;
    float* a_d  = ws + 20586496;
    int*   iw   = (int*)(ws + 20652032);
    int*   deg    = iw;
    int*   rowptr = iw + 8192;                           // 8193
    int*   cursor = iw + 16392;
    int*   col    = iw + 24592;                          // 270336

    // ---- casts ----
    castw_kernel<<<2705, 256, 0, stream>>>(gat_W0, gat_W12, qkv_w, out_w, ff1_w, ff2_w,
                                           W0b, W12b, qkv_wb, out_wb, ff1_wb, ff2_wb);
    castf_kernel<<<512, 256, 0, stream>>>(x, xb, 131072);

    // ---- CSR build ----
    hipMemsetAsync(deg, 0, NN * sizeof(int), stream);
    int etot = EE + NN;
    count_kernel<<<(etot + 255) / 256, 256, 0, stream>>>(ei, deg);
    scan_kernel<<<1, 1024, 0, stream>>>(deg, rowptr, cursor);
    scatter_kernel<<<(etot + 255) / 256, 256, 0, stream>>>(ei, cursor, col);

    // ---- GAT layer 0 ----
    mgemm_kernel<false, false, false, true, false><<<dim3(64, 2), 256, 0, stream>>>(
        xb, W0b, nullptr, nullptr, hA, nullptr, NN, DD, 64);
    asd_kernel<<<256, 256, 0, stream>>>(hA, att_src, att_dst, a_s, a_d);
    gat_agg_kernel<<<2048, 256, 0, stream>>>(hA, a_s, a_d, rowptr, col, gat_bias, hB, hBb);

    // ---- GAT layers 1,2 ----
    for (int l = 0; l < 2; ++l) {
        mgemm_kernel<false, false, false, true, false><<<dim3(64, 2), 256, 0, stream>>>(
            hBb, W12b + (size_t)l * DD * DD, nullptr, nullptr, hA, nullptr, NN, DD, DD);
        asd_kernel<<<256, 256, 0, stream>>>(
            hA, att_src + (l + 1) * 256, att_dst + (l + 1) * 256, a_s, a_d);
        gat_agg_kernel<<<2048, 256, 0, stream>>>(
            hA, a_s, a_d, rowptr, col, gat_bias + (l + 1) * 256, hB, hBb);
    }

    // ---- Transformer layers ----
    for (int l = 0; l < 2; ++l) {
        mgemm_kernel<true, false, false, false, true><<<dim3(64, 6), 256, 0, stream>>>(
            hBb, qkv_wb + (size_t)l * 768 * DD, qkv_b + l * 768, nullptr,
            nullptr, qb16, NN, 768, DD);
        cast_qkv_kernel<<<24576, 256, 0, stream>>>(qb16, Qb, Kb, Vt);
        attn_mfma_kernel<<<dim3(64, 64), 256, 0, stream>>>(Qb, Kb, Vt, attnb);
        mgemm_kernel<true, false, true, true, false><<<dim3(64, 2), 256, 0, stream>>>(
            attnb, out_wb + (size_t)l * DD * DD, out_b + l * DD, hB,
            hA, nullptr, NN, DD, DD);
        ln_kernel<<<2048, 256, 0, stream>>>(hA, ln1_w + l * DD, ln1_b + l * DD, lnb);
        mgemm_kernel<true, true, false, false, true><<<dim3(64, 16), 256, 0, stream>>>(
            lnb, ff1_wb + (size_t)l * DFFN * DD, ff1_b + l * DFFN, nullptr,
            nullptr, ffb, NN, DFFN, DD);
        mgemm_kernel<true, false, true, true, false><<<dim3(64, 2), 256, 0, stream>>>(
            ffb, ff2_wb + (size_t)l * DD * DFFN, ff2_b + l * DD, hA,
            hB, nullptr, NN, DD, DFFN);
        ln_kernel<<<2048, 256, 0, stream>>>(hB, ln2_w + l * DD, ln2_b + l * DD, hBb);
    }

    // ---- prediction head ----
    pred_kernel<<<96, 256, 0, stream>>>(hB, pred_w, pred_b, outp);
}

// Round 4
// 598.026 us; speedup vs baseline: 3.6727x; 1.0798x over previous
//
#include <hip/hip_runtime.h>
#include <hip/hip_bf16.h>

#define NN 8192
#define EE 262144
#define BB 8
#define LL 1024
#define HH 8
#define DD 256
#define DFFN 2048

typedef short s8v __attribute__((ext_vector_type(8)));
typedef float f32x4 __attribute__((ext_vector_type(4)));
typedef unsigned short ushort;

__device__ inline ushort f2bf(float f) {
    unsigned u = __float_as_uint(f);
    u = (u + 0x7fffu + ((u >> 16) & 1u)) >> 16;
    return (ushort)u;
}
__device__ inline float bf2f(ushort u) {
    return __uint_as_float(((unsigned)u) << 16);
}

// ---------------------------------------------------------------------------
// bf16 MFMA GEMM (m97 structure): C[M,N] = A[M,K] @ W[N,K]^T
// ---------------------------------------------------------------------------
template<bool BIAS, bool RELU, bool RES, bool WF, bool WB>
__global__ __launch_bounds__(256) void mgemm_kernel(
    const ushort* __restrict__ A, const ushort* __restrict__ W,
    const float* __restrict__ bias, const float* __restrict__ res,
    float* __restrict__ Cf, ushort* __restrict__ Cb, int M, int N, int K)
{
    __shared__ ushort As[128 * 32];
    __shared__ ushort Bs[128 * 32];
    int t = threadIdx.x;
    int l = t & 63;
    int quad = l >> 4, l15 = l & 15;
    int w = t >> 6;
    int wm = (w >> 1) * 64, wn = (w & 1) * 64;
    int m0 = blockIdx.x * 128, n0 = blockIdx.y * 128;

    f32x4 z = {0.f, 0.f, 0.f, 0.f};
    f32x4 acc[4][4];
#pragma unroll
    for (int i = 0; i < 4; ++i)
#pragma unroll
        for (int j = 0; j < 4; ++j) acc[i][j] = z;

    for (int k0 = 0; k0 < K; k0 += 32) {
#pragma unroll
        for (int i = 0; i < 2; ++i) {
            int chunk = i * 256 + t;
            int e = chunk * 8;
            int r = e >> 5, c = e & 31;
            __builtin_amdgcn_global_load_lds(
                (const __attribute__((address_space(1))) unsigned int*)
                    (A + (size_t)(m0 + r) * K + k0 + c),
                (__attribute__((address_space(3))) unsigned int*)(As + e), 16, 0, 0);
            __builtin_amdgcn_global_load_lds(
                (const __attribute__((address_space(1))) unsigned int*)
                    (W + (size_t)(n0 + r) * K + k0 + c),
                (__attribute__((address_space(3))) unsigned int*)(Bs + e), 16, 0, 0);
        }
        __syncthreads();
        s8v af[4], bfv[4];
#pragma unroll
        for (int i = 0; i < 4; ++i) {
            af[i]  = *(const s8v*)(As + (wm + i * 16 + l15) * 32 + quad * 8);
            bfv[i] = *(const s8v*)(Bs + (wn + i * 16 + l15) * 32 + quad * 8);
        }
#pragma unroll
        for (int mi = 0; mi < 4; ++mi)
#pragma unroll
            for (int ni = 0; ni < 4; ++ni)
                acc[mi][ni] = __builtin_amdgcn_mfma_f32_16x16x32_bf16(
                    af[mi], bfv[ni], acc[mi][ni], 0, 0, 0);
        __syncthreads();
    }

#pragma unroll
    for (int mi = 0; mi < 4; ++mi) {
#pragma unroll
        for (int ni = 0; ni < 4; ++ni) {
            int n = n0 + wn + ni * 16 + l15;
#pragma unroll
            for (int r = 0; r < 4; ++r) {
                int m = m0 + wm + mi * 16 + quad * 4 + r;
                float v = acc[mi][ni][r];
                if (BIAS) v += bias[n];
                if (RES)  v += res[(size_t)m * N + n];
                if (RELU) v = fmaxf(v, 0.f);
                if (WF) Cf[(size_t)m * N + n] = v;
                if (WB) Cb[(size_t)m * N + n] = f2bf(v);
            }
        }
    }
}

// ---------------------------------------------------------------------------
// qkv GEMM with fused re-layout epilogue: writes Qb/Kb [bh][1024][32]
// (Q scaled) and Vt [bh][32][1024] directly. N=768 fixed.
// ---------------------------------------------------------------------------
__global__ __launch_bounds__(256) void mgemm_qkv_kernel(
    const ushort* __restrict__ A, const ushort* __restrict__ W,
    const float* __restrict__ bias,
    ushort* __restrict__ Qb, ushort* __restrict__ Kb, ushort* __restrict__ Vt,
    int M, int K)
{
    __shared__ ushort As[128 * 32];
    __shared__ ushort Bs[128 * 32];
    int t = threadIdx.x;
    int l = t & 63;
    int quad = l >> 4, l15 = l & 15;
    int w = t >> 6;
    int wm = (w >> 1) * 64, wn = (w & 1) * 64;
    int m0 = blockIdx.x * 128, n0 = blockIdx.y * 128;

    f32x4 z = {0.f, 0.f, 0.f, 0.f};
    f32x4 acc[4][4];
#pragma unroll
    for (int i = 0; i < 4; ++i)
#pragma unroll
        for (int j = 0; j < 4; ++j) acc[i][j] = z;

    for (int k0 = 0; k0 < K; k0 += 32) {
#pragma unroll
        for (int i = 0; i < 2; ++i) {
            int chunk = i * 256 + t;
            int e = chunk * 8;
            int r = e >> 5, c = e & 31;
            __builtin_amdgcn_global_load_lds(
                (const __attribute__((address_space(1))) unsigned int*)
                    (A + (size_t)(m0 + r) * K + k0 + c),
                (__attribute__((address_space(3))) unsigned int*)(As + e), 16, 0, 0);
            __builtin_amdgcn_global_load_lds(
                (const __attribute__((address_space(1))) unsigned int*)
                    (W + (size_t)(n0 + r) * K + k0 + c),
                (__attribute__((address_space(3))) unsigned int*)(Bs + e), 16, 0, 0);
        }
        __syncthreads();
        s8v af[4], bfv[4];
#pragma unroll
        for (int i = 0; i < 4; ++i) {
            af[i]  = *(const s8v*)(As + (wm + i * 16 + l15) * 32 + quad * 8);
            bfv[i] = *(const s8v*)(Bs + (wn + i * 16 + l15) * 32 + quad * 8);
        }
#pragma unroll
        for (int mi = 0; mi < 4; ++mi)
#pragma unroll
            for (int ni = 0; ni < 4; ++ni)
                acc[mi][ni] = __builtin_amdgcn_mfma_f32_16x16x32_bf16(
                    af[mi], bfv[ni], acc[mi][ni], 0, 0, 0);
        __syncthreads();
    }

#pragma unroll
    for (int mi = 0; mi < 4; ++mi) {
#pragma unroll
        for (int ni = 0; ni < 4; ++ni) {
            int n = n0 + wn + ni * 16 + l15;
            int sec = n >> 8, hc = n & 255;
            int hh = hc >> 5, c = hc & 31;
            float bv = bias[n];
#pragma unroll
            for (int r = 0; r < 4; ++r) {
                int m = m0 + wm + mi * 16 + quad * 4 + r;
                float v = acc[mi][ni][r] + bv;
                int b = m >> 10, ll2 = m & 1023;
                int bh = b * 8 + hh;
                if (sec == 0)
                    Qb[(size_t)bh * 32768 + ll2 * 32 + c] = f2bf(v * 0.17677669529663687f);
                else if (sec == 1)
                    Kb[(size_t)bh * 32768 + ll2 * 32 + c] = f2bf(v);
                else
                    Vt[(size_t)bh * 32768 + c * 1024 + ll2] = f2bf(v);
            }
        }
    }
}

// ---------------------------------------------------------------------------
// Weight casts fp32 -> bf16
// ---------------------------------------------------------------------------
__global__ __launch_bounds__(256) void castw_kernel(
    const float* __restrict__ W0, const float* __restrict__ W12,
    const float* __restrict__ qkvw, const float* __restrict__ outw,
    const float* __restrict__ f1w, const float* __restrict__ f2w,
    ushort* __restrict__ W0b, ushort* __restrict__ W12b,
    ushort* __restrict__ qkvb, ushort* __restrict__ outb,
    ushort* __restrict__ f1b, ushort* __restrict__ f2b)
{
    int e = (blockIdx.x * 256 + threadIdx.x) * 4;
    if (e >= 2768896) return;
    const float* s; ushort* d; int off;
    if (e < 16384)        { s = W0;   d = W0b;  off = e; }
    else if (e < 147456)  { s = W12;  d = W12b; off = e - 16384; }
    else if (e < 540672)  { s = qkvw; d = qkvb; off = e - 147456; }
    else if (e < 671744)  { s = outw; d = outb; off = e - 540672; }
    else if (e < 1720320) { s = f1w;  d = f1b;  off = e - 671744; }
    else                  { s = f2w;  d = f2b;  off = e - 1720320; }
    float4 v = *(const float4*)(s + off);
    d[off + 0] = f2bf(v.x); d[off + 1] = f2bf(v.y);
    d[off + 2] = f2bf(v.z); d[off + 3] = f2bf(v.w);
}

__global__ __launch_bounds__(256) void castf_kernel(
    const float* __restrict__ s, ushort* __restrict__ d, int n4)
{
    int i = blockIdx.x * 256 + threadIdx.x;
    if (i >= n4) return;
    float4 v = *(const float4*)(s + i * 4);
    d[i * 4 + 0] = f2bf(v.x); d[i * 4 + 1] = f2bf(v.y);
    d[i * 4 + 2] = f2bf(v.z); d[i * 4 + 3] = f2bf(v.w);
}

// ---------------------------------------------------------------------------
// GAT logits
// ---------------------------------------------------------------------------
__global__ __launch_bounds__(256) void asd_kernel(
    const float* __restrict__ h, const float* __restrict__ atts,
    const float* __restrict__ attd, float* __restrict__ a_s, float* __restrict__ a_d)
{
    int idx = blockIdx.x * 256 + threadIdx.x;
    int n = idx >> 3, hh = idx & 7;
    const float* hr = h + (size_t)n * DD + hh * 32;
    const float* sr = atts + hh * 32;
    const float* dr = attd + hh * 32;
    float ss = 0.f, sd = 0.f;
#pragma unroll
    for (int c = 0; c < 32; ++c) { float v = hr[c]; ss += v * sr[c]; sd += v * dr[c]; }
    a_s[idx] = ss; a_d[idx] = sd;
}

// ---------------------------------------------------------------------------
// CSR build
// ---------------------------------------------------------------------------
__global__ void count_kernel(const int* __restrict__ ei, int* __restrict__ deg)
{
    int e = blockIdx.x * 256 + threadIdx.x;
    if (e >= EE + NN) return;
    int d = (e < EE) ? ei[EE + e] : (e - EE);
    atomicAdd(&deg[d], 1);
}

__global__ __launch_bounds__(1024) void scan_kernel(
    const int* __restrict__ deg, int* __restrict__ rowptr, int* __restrict__ cursor)
{
    __shared__ int part[1024];
    int t = threadIdx.x;
    int base = t * 8;
    int loc[8]; int s = 0;
#pragma unroll
    for (int i = 0; i < 8; ++i) { loc[i] = deg[base + i]; s += loc[i]; }
    part[t] = s;
    __syncthreads();
    for (int off = 1; off < 1024; off <<= 1) {
        int v = (t >= off) ? part[t - off] : 0;
        __syncthreads();
        part[t] += v;
        __syncthreads();
    }
    int run = (t == 0) ? 0 : part[t - 1];
#pragma unroll
    for (int i = 0; i < 8; ++i) { rowptr[base + i] = run; cursor[base + i] = run; run += loc[i]; }
    if (t == 1023) rowptr[NN] = run;
}

__global__ void scatter_kernel(const int* __restrict__ ei, int* __restrict__ cursor,
                               int* __restrict__ col)
{
    int e = blockIdx.x * 256 + threadIdx.x;
    if (e >= EE + NN) return;
    int s, d;
    if (e < EE) { s = ei[e]; d = ei[EE + e]; } else { s = e - EE; d = s; }
    int slot = atomicAdd(&cursor[d], 1);
    col[slot] = s;
}

// ---------------------------------------------------------------------------
// GAT aggregation: one wave per dst node; 2 passes (no max subtraction —
// logits are O(0.1), softmax is shift-invariant).
// ---------------------------------------------------------------------------
__global__ __launch_bounds__(256) void gat_agg_kernel(
    const float* __restrict__ hlin, const float* __restrict__ a_s,
    const float* __restrict__ a_d, const int* __restrict__ rowptr,
    const int* __restrict__ col, const float* __restrict__ bias,
    float* __restrict__ out, ushort* __restrict__ outb)
{
    int wid = threadIdx.x >> 6, lane = threadIdx.x & 63;
    int dst = blockIdx.x * 4 + wid;
    int start = rowptr[dst], end = rowptr[dst + 1];
    float ad[HH];
#pragma unroll
    for (int h = 0; h < HH; ++h) ad[h] = a_d[(size_t)dst * HH + h];

    float sm[HH];
#pragma unroll
    for (int h = 0; h < HH; ++h) sm[h] = 0.f;
    for (int e = start + lane; e < end; e += 64) {
        int s = col[e];
#pragma unroll
        for (int h = 0; h < HH; ++h) {
            float v = a_s[(size_t)s * HH + h] + ad[h];
            v = v > 0.f ? v : 0.2f * v;
            sm[h] += __expf(v);
        }
    }
#pragma unroll
    for (int h = 0; h < HH; ++h)
#pragma unroll
        for (int off = 32; off; off >>= 1) sm[h] += __shfl_xor(sm[h], off);

    int myh = lane >> 3;
    float sh = sm[myh], adh = ad[myh];
    float4 acc = make_float4(0.f, 0.f, 0.f, 0.f);
    for (int e = start; e < end; ++e) {
        int s = col[e];
        float v = a_s[(size_t)s * HH + myh] + adh;
        v = v > 0.f ? v : 0.2f * v;
        float alpha = __expf(v) / sh;
        float4 hv = *(const float4*)(hlin + (size_t)s * DD + lane * 4);
        acc.x += alpha * hv.x; acc.y += alpha * hv.y;
        acc.z += alpha * hv.z; acc.w += alpha * hv.w;
    }
    float4 bv = *(const float4*)(bias + lane * 4);
    float r0 = fmaxf(acc.x + bv.x, 0.f);
    float r1 = fmaxf(acc.y + bv.y, 0.f);
    float r2 = fmaxf(acc.z + bv.z, 0.f);
    float r3 = fmaxf(acc.w + bv.w, 0.f);
    float* op = out + (size_t)dst * DD + lane * 4;
    op[0] = r0; op[1] = r1; op[2] = r2; op[3] = r3;
    ushort* ob = outb + (size_t)dst * DD + lane * 4;
    ob[0] = f2bf(r0); ob[1] = f2bf(r1); ob[2] = f2bf(r2); ob[3] = f2bf(r3);
}

// ---------------------------------------------------------------------------
// Flash-style MFMA attention. Block = 64 q-rows (4 waves x 16) of one bh.
// 8 chunks of 128 keys; K,V^T staged in LDS per block; per-wave online
// softmax; P transposed via per-wave LDS buffer.
// ---------------------------------------------------------------------------
__global__ __launch_bounds__(256, 4) void attn_flash_kernel(
    const ushort* __restrict__ Qb, const ushort* __restrict__ Kb,
    const ushort* __restrict__ Vt, ushort* __restrict__ outb)
{
    __shared__ ushort Ks[128 * 32];        // [key][c]
    __shared__ ushort Vs[32 * 128];        // [c][key]
    __shared__ ushort pw[4][16][132];      // per-wave P [qrow][key]

    int t = threadIdx.x;
    int w = t >> 6, lane = t & 63;
    int quad = lane >> 4, l15 = lane & 15;
    int bh = blockIdx.y;
    int q0 = blockIdx.x * 64 + w * 16;
    int b = bh >> 3, h = bh & 7;

    const ushort* qbase = Qb + (size_t)bh * 32768;
    const ushort* kbase = Kb + (size_t)bh * 32768;
    const ushort* vbase = Vt + (size_t)bh * 32768;

    s8v aq = *(const s8v*)(qbase + (q0 + l15) * 32 + quad * 8);

    f32x4 z = {0.f, 0.f, 0.f, 0.f};
    f32x4 o0 = z, o1 = z;
    float m[4] = {-1e30f, -1e30f, -1e30f, -1e30f};
    float lden[4] = {0.f, 0.f, 0.f, 0.f};

    for (int ch = 0; ch < 8; ++ch) {
        int j0 = ch * 128;
        // stage K chunk (contiguous 8 KB) and V chunk (32 rows x 256 B)
#pragma unroll
        for (int i = 0; i < 2; ++i) {
            int idx = i * 256 + t;
            __builtin_amdgcn_global_load_lds(
                (const __attribute__((address_space(1))) unsigned int*)
                    (kbase + (size_t)j0 * 32 + idx * 8),
                (__attribute__((address_space(3))) unsigned int*)(Ks + idx * 8), 16, 0, 0);
            int vr = idx >> 4, vc = (idx & 15) * 8;
            __builtin_amdgcn_global_load_lds(
                (const __attribute__((address_space(1))) unsigned int*)
                    (vbase + (size_t)vr * 1024 + j0 + vc),
                (__attribute__((address_space(3))) unsigned int*)(Vs + idx * 8), 16, 0, 0);
        }
        __syncthreads();

        // QK^T: 8 MFMAs -> scores s[kk], row=quad*4+r, key=kk*16+l15
        f32x4 s[8];
#pragma unroll
        for (int kk = 0; kk < 8; ++kk) {
            s8v bk = *(const s8v*)(Ks + (kk * 16 + l15) * 32 + quad * 8);
            s[kk] = __builtin_amdgcn_mfma_f32_16x16x32_bf16(aq, bk, z, 0, 0, 0);
        }

        // online softmax update (per row)
        float cm[4], cs[4], sc[4];
#pragma unroll
        for (int r = 0; r < 4; ++r) {
            float v = s[0][r];
#pragma unroll
            for (int kk = 1; kk < 8; ++kk) v = fmaxf(v, s[kk][r]);
#pragma unroll
            for (int off = 1; off < 16; off <<= 1) v = fmaxf(v, __shfl_xor(v, off));
            float mn = fmaxf(m[r], v);
            sc[r] = __expf(m[r] - mn);
            m[r] = mn;
            cs[r] = 0.f;
        }
#pragma unroll
        for (int kk = 0; kk < 8; ++kk) {
#pragma unroll
            for (int r = 0; r < 4; ++r) {
                float p = __expf(s[kk][r] - m[r]);
                cs[r] += p;
                pw[w][quad * 4 + r][kk * 16 + l15] = f2bf(p);
            }
        }
#pragma unroll
        for (int r = 0; r < 4; ++r) {
#pragma unroll
            for (int off = 1; off < 16; off <<= 1) cs[r] += __shfl_xor(cs[r], off);
            lden[r] = lden[r] * sc[r] + cs[r];
            o0[r] *= sc[r];
            o1[r] *= sc[r];
        }

        // PV: P(16x128) x V^T chunks -> accumulate o
#pragma unroll
        for (int kk = 0; kk < 4; ++kk) {
            s8v ap = *(const s8v*)(&pw[w][l15][kk * 32 + quad * 8]);
            s8v b0 = *(const s8v*)(Vs + (size_t)l15 * 128 + kk * 32 + quad * 8);
            s8v b1 = *(const s8v*)(Vs + (size_t)(16 + l15) * 128 + kk * 32 + quad * 8);
            o0 = __builtin_amdgcn_mfma_f32_16x16x32_bf16(ap, b0, o0, 0, 0, 0);
            o1 = __builtin_amdgcn_mfma_f32_16x16x32_bf16(ap, b1, o1, 0, 0, 0);
        }
        __syncthreads();
    }

#pragma unroll
    for (int r = 0; r < 4; ++r) {
        int row = q0 + quad * 4 + r;
        float inv = 1.f / lden[r];
        outb[(size_t)(b * 1024 + row) * 256 + h * 32 + l15]      = f2bf(o0[r] * inv);
        outb[(size_t)(b * 1024 + row) * 256 + h * 32 + 16 + l15] = f2bf(o1[r] * inv);
    }
}

// ---------------------------------------------------------------------------
// LayerNorm in place (fp32) + bf16 copy out.
// ---------------------------------------------------------------------------
__global__ __launch_bounds__(256) void ln_kernel(
    float* __restrict__ x, const float* __restrict__ w, const float* __restrict__ b,
    ushort* __restrict__ xb)
{
    int wid = threadIdx.x >> 6, lane = threadIdx.x & 63;
    size_t row = blockIdx.x * 4 + wid;
    float4 v = *(float4*)(x + row * DD + lane * 4);
    float s = v.x + v.y + v.z + v.w;
#pragma unroll
    for (int off = 32; off; off >>= 1) s += __shfl_xor(s, off);
    float mu = s * (1.f / 256.f);
    float dx = v.x - mu, dy = v.y - mu, dz = v.z - mu, dw = v.w - mu;
    float q = dx * dx + dy * dy + dz * dz + dw * dw;
#pragma unroll
    for (int off = 32; off; off >>= 1) q += __shfl_xor(q, off);
    float rstd = rsqrtf(q * (1.f / 256.f) + 1e-5f);
    int c = lane * 4;
    float4 wv = *(const float4*)(w + c);
    float4 bv = *(const float4*)(b + c);
    float4 o;
    o.x = dx * rstd * wv.x + bv.x;
    o.y = dy * rstd * wv.y + bv.y;
    o.z = dz * rstd * wv.z + bv.z;
    o.w = dw * rstd * wv.w + bv.w;
    *(float4*)(x + row * DD + c) = o;
    ushort* ob = xb + row * DD + c;
    ob[0] = f2bf(o.x); ob[1] = f2bf(o.y); ob[2] = f2bf(o.z); ob[3] = f2bf(o.w);
}

// ---------------------------------------------------------------------------
// Final prediction head
// ---------------------------------------------------------------------------
__global__ __launch_bounds__(256) void pred_kernel(
    const float* __restrict__ x, const float* __restrict__ w,
    const float* __restrict__ b, float* __restrict__ out)
{
    int idx = blockIdx.x * 256 + threadIdx.x;
    int m = idx / 3, o = idx % 3;
    const float* xr = x + (size_t)m * DD;
    const float* wr = w + o * DD;
    float s = b[o];
#pragma unroll 8
    for (int c = 0; c < DD; ++c) s += xr[c] * wr[c];
    out[idx] = s;
}

// ---------------------------------------------------------------------------
extern "C" void kernel_launch(void* const* d_in, const int* in_sizes, int n_in,
                              void* d_out, int out_size, void* d_ws, size_t ws_size,
                              hipStream_t stream)
{
    const float* x        = (const float*)d_in[0];
    const int*   ei       = (const int*)d_in[1];
    const float* gat_W0   = (const float*)d_in[3];
    const float* gat_W12  = (const float*)d_in[4];
    const float* att_src  = (const float*)d_in[5];
    const float* att_dst  = (const float*)d_in[6];
    const float* gat_bias = (const float*)d_in[7];
    const float* qkv_w    = (const float*)d_in[8];
    const float* qkv_b    = (const float*)d_in[9];
    const float* out_w    = (const float*)d_in[10];
    const float* out_b    = (const float*)d_in[11];
    const float* ln1_w    = (const float*)d_in[12];
    const float* ln1_b    = (const float*)d_in[13];
    const float* ln2_w    = (const float*)d_in[14];
    const float* ln2_b    = (const float*)d_in[15];
    const float* ff1_w    = (const float*)d_in[16];
    const float* ff1_b    = (const float*)d_in[17];
    const float* ff2_w    = (const float*)d_in[18];
    const float* ff2_b    = (const float*)d_in[19];
    const float* pred_w   = (const float*)d_in[20];
    const float* pred_b   = (const float*)d_in[21];
    float* outp = (float*)d_out;

    float* ws   = (float*)d_ws;
    float* hA   = ws;                                    // [8192,256] f32
    float* hB   = ws + 2097152;                          // [8192,256] f32
    ushort* ffb  = (ushort*)(ws + 4194304);              // [8192,2048] bf16
    ushort* Qb   = (ushort*)(ws + 12582912);             // [64][1024][32]
    ushort* Kb   = (ushort*)(ws + 13631488);
    ushort* Vt   = (ushort*)(ws + 14680064);             // [64][32][1024]
    ushort* attnb= (ushort*)(ws + 15728640);             // [8192,256] bf16
    ushort* lnb  = (ushort*)(ws + 16777216);             // [8192,256] bf16
    ushort* hBb  = (ushort*)(ws + 17825792);             // [8192,256] bf16
    ushort* xb   = (ushort*)(ws + 18874368);             // [8192,64] bf16
    ushort* wbase= (ushort*)(ws + 19136512);
    ushort* W0b    = wbase;
    ushort* W12b   = wbase + 16384;
    ushort* qkv_wb = wbase + 147456;
    ushort* out_wb = wbase + 540672;
    ushort* ff1_wb = wbase + 671744;
    ushort* ff2_wb = wbase + 1720320;
    float* a_s  = ws + 20520960;
    float* a_d  = ws + 20586496;
    int*   iw   = (int*)(ws + 20652032);
    int*   deg    = iw;
    int*   rowptr = iw + 8192;
    int*   cursor = iw + 16392;
    int*   col    = iw + 24592;

    // ---- casts ----
    castw_kernel<<<2705, 256, 0, stream>>>(gat_W0, gat_W12, qkv_w, out_w, ff1_w, ff2_w,
                                           W0b, W12b, qkv_wb, out_wb, ff1_wb, ff2_wb);
    castf_kernel<<<512, 256, 0, stream>>>(x, xb, 131072);

    // ---- CSR build ----
    hipMemsetAsync(deg, 0, NN * sizeof(int), stream);
    int etot = EE + NN;
    count_kernel<<<(etot + 255) / 256, 256, 0, stream>>>(ei, deg);
    scan_kernel<<<1, 1024, 0, stream>>>(deg, rowptr, cursor);
    scatter_kernel<<<(etot + 255) / 256, 256, 0, stream>>>(ei, cursor, col);

    // ---- GAT layer 0 ----
    mgemm_kernel<false, false, false, true, false><<<dim3(64, 2), 256, 0, stream>>>(
        xb, W0b, nullptr, nullptr, hA, nullptr, NN, DD, 64);
    asd_kernel<<<256, 256, 0, stream>>>(hA, att_src, att_dst, a_s, a_d);
    gat_agg_kernel<<<2048, 256, 0, stream>>>(hA, a_s, a_d, rowptr, col, gat_bias, hB, hBb);

    // ---- GAT layers 1,2 ----
    for (int l = 0; l < 2; ++l) {
        mgemm_kernel<false, false, false, true, false><<<dim3(64, 2), 256, 0, stream>>>(
            hBb, W12b + (size_t)l * DD * DD, nullptr, nullptr, hA, nullptr, NN, DD, DD);
        asd_kernel<<<256, 256, 0, stream>>>(
            hA, att_src + (l + 1) * 256, att_dst + (l + 1) * 256, a_s, a_d);
        gat_agg_kernel<<<2048, 256, 0, stream>>>(
            hA, a_s, a_d, rowptr, col, gat_bias + (l + 1) * 256, hB, hBb);
    }

    // ---- Transformer layers ----
    for (int l = 0; l < 2; ++l) {
        mgemm_qkv_kernel<<<dim3(64, 6), 256, 0, stream>>>(
            hBb, qkv_wb + (size_t)l * 768 * DD, qkv_b + l * 768, Qb, Kb, Vt, NN, DD);
        attn_flash_kernel<<<dim3(16, 64), 256, 0, stream>>>(Qb, Kb, Vt, attnb);
        mgemm_kernel<true, false, true, true, false><<<dim3(64, 2), 256, 0, stream>>>(
            attnb, out_wb + (size_t)l * DD * DD, out_b + l * DD, hB,
            hA, nullptr, NN, DD, DD);
        ln_kernel<<<2048, 256, 0, stream>>>(hA, ln1_w + l * DD, ln1_b + l * DD, lnb);
        mgemm_kernel<true, true, false, false, true><<<dim3(64, 16), 256, 0, stream>>>(
            lnb, ff1_wb + (size_t)l * DFFN * DD, ff1_b + l * DFFN, nullptr,
            nullptr, ffb, NN, DFFN, DD);
        mgemm_kernel<true, false, true, true, false><<<dim3(64, 2), 256, 0, stream>>>(
            ffb, ff2_wb + (size_t)l * DD * DFFN, ff2_b + l * DD, hA,
            hB, nullptr, NN, DD, DFFN);
        ln_kernel<<<2048, 256, 0, stream>>>(hB, ln2_w + l * DD, ln2_b + l * DD, hBb);
    }

    // ---- prediction head ----
    pred_kernel<<<96, 256, 0, stream>>>(hB, pred_w, pred_b, outp);
}

// Round 5
// 569.394 us; speedup vs baseline: 3.8574x; 1.0503x over previous
//
#include <hip/hip_runtime.h>
#include <hip/hip_bf16.h>

#define NN 8192
#define EE 262144
#define BB 8
#define LL 1024
#define HH 8
#define DD 256
#define DFFN 2048

typedef short s8v __attribute__((ext_vector_type(8)));
typedef float f32x4 __attribute__((ext_vector_type(4)));
typedef unsigned short ushort;

__device__ inline ushort f2bf(float f) {
    unsigned u = __float_as_uint(f);
    u = (u + 0x7fffu + ((u >> 16) & 1u)) >> 16;
    return (ushort)u;
}
__device__ inline float bf2f(ushort u) {
    return __uint_as_float(((unsigned)u) << 16);
}

// ---------------------------------------------------------------------------
// bf16 MFMA GEMM: C[M,N] = A[M,K] @ W[N,K]^T.  128x128 tile, BK=32.
// LDS chunks XOR-swizzled (source-permuted at global_load_lds) so fragment
// ds_read_b128 is 2-way (free) instead of 8-way.
// ---------------------------------------------------------------------------
template<bool BIAS, bool RELU, bool RES, bool WF, bool WB>
__global__ __launch_bounds__(256) void mgemm_kernel(
    const ushort* __restrict__ A, const ushort* __restrict__ W,
    const float* __restrict__ bias, const float* __restrict__ res,
    float* __restrict__ Cf, ushort* __restrict__ Cb, int M, int N, int K)
{
    __shared__ ushort As[128 * 32];
    __shared__ ushort Bs[128 * 32];
    int t = threadIdx.x;
    int l = t & 63;
    int quad = l >> 4, l15 = l & 15;
    int swz = (l15 >> 1) & 3;            // lane-constant read swizzle
    int rq = (quad ^ swz) * 8;
    int w = t >> 6;
    int wm = (w >> 1) * 64, wn = (w & 1) * 64;
    int m0 = blockIdx.x * 128, n0 = blockIdx.y * 128;

    f32x4 z = {0.f, 0.f, 0.f, 0.f};
    f32x4 acc[4][4];
#pragma unroll
    for (int i = 0; i < 4; ++i)
#pragma unroll
        for (int j = 0; j < 4; ++j) acc[i][j] = z;

    for (int k0 = 0; k0 < K; k0 += 32) {
#pragma unroll
        for (int i = 0; i < 2; ++i) {
            int chunk = i * 256 + t;          // 0..511
            int r = chunk >> 2, q = chunk & 3;
            int qs = (q ^ ((r >> 1) & 3)) * 8;
            __builtin_amdgcn_global_load_lds(
                (const __attribute__((address_space(1))) unsigned int*)
                    (A + (size_t)(m0 + r) * K + k0 + qs),
                (__attribute__((address_space(3))) unsigned int*)(As + chunk * 8), 16, 0, 0);
            __builtin_amdgcn_global_load_lds(
                (const __attribute__((address_space(1))) unsigned int*)
                    (W + (size_t)(n0 + r) * K + k0 + qs),
                (__attribute__((address_space(3))) unsigned int*)(Bs + chunk * 8), 16, 0, 0);
        }
        __syncthreads();
        s8v af[4], bfv[4];
#pragma unroll
        for (int i = 0; i < 4; ++i) {
            af[i]  = *(const s8v*)(As + (wm + i * 16 + l15) * 32 + rq);
            bfv[i] = *(const s8v*)(Bs + (wn + i * 16 + l15) * 32 + rq);
        }
#pragma unroll
        for (int mi = 0; mi < 4; ++mi)
#pragma unroll
            for (int ni = 0; ni < 4; ++ni)
                acc[mi][ni] = __builtin_amdgcn_mfma_f32_16x16x32_bf16(
                    af[mi], bfv[ni], acc[mi][ni], 0, 0, 0);
        __syncthreads();
    }

#pragma unroll
    for (int mi = 0; mi < 4; ++mi) {
#pragma unroll
        for (int ni = 0; ni < 4; ++ni) {
            int n = n0 + wn + ni * 16 + l15;
#pragma unroll
            for (int r = 0; r < 4; ++r) {
                int m = m0 + wm + mi * 16 + quad * 4 + r;
                float v = acc[mi][ni][r];
                if (BIAS) v += bias[n];
                if (RES)  v += res[(size_t)m * N + n];
                if (RELU) v = fmaxf(v, 0.f);
                if (WF) Cf[(size_t)m * N + n] = v;
                if (WB) Cb[(size_t)m * N + n] = f2bf(v);
            }
        }
    }
}

// ---------------------------------------------------------------------------
// qkv GEMM with fused re-layout epilogue -> Qb/Kb [bh][1024][32], Vt [bh][32][1024]
// ---------------------------------------------------------------------------
__global__ __launch_bounds__(256) void mgemm_qkv_kernel(
    const ushort* __restrict__ A, const ushort* __restrict__ W,
    const float* __restrict__ bias,
    ushort* __restrict__ Qb, ushort* __restrict__ Kb, ushort* __restrict__ Vt,
    int M, int K)
{
    __shared__ ushort As[128 * 32];
    __shared__ ushort Bs[128 * 32];
    int t = threadIdx.x;
    int l = t & 63;
    int quad = l >> 4, l15 = l & 15;
    int swz = (l15 >> 1) & 3;
    int rq = (quad ^ swz) * 8;
    int w = t >> 6;
    int wm = (w >> 1) * 64, wn = (w & 1) * 64;
    int m0 = blockIdx.x * 128, n0 = blockIdx.y * 128;

    f32x4 z = {0.f, 0.f, 0.f, 0.f};
    f32x4 acc[4][4];
#pragma unroll
    for (int i = 0; i < 4; ++i)
#pragma unroll
        for (int j = 0; j < 4; ++j) acc[i][j] = z;

    for (int k0 = 0; k0 < K; k0 += 32) {
#pragma unroll
        for (int i = 0; i < 2; ++i) {
            int chunk = i * 256 + t;
            int r = chunk >> 2, q = chunk & 3;
            int qs = (q ^ ((r >> 1) & 3)) * 8;
            __builtin_amdgcn_global_load_lds(
                (const __attribute__((address_space(1))) unsigned int*)
                    (A + (size_t)(m0 + r) * K + k0 + qs),
                (__attribute__((address_space(3))) unsigned int*)(As + chunk * 8), 16, 0, 0);
            __builtin_amdgcn_global_load_lds(
                (const __attribute__((address_space(1))) unsigned int*)
                    (W + (size_t)(n0 + r) * K + k0 + qs),
                (__attribute__((address_space(3))) unsigned int*)(Bs + chunk * 8), 16, 0, 0);
        }
        __syncthreads();
        s8v af[4], bfv[4];
#pragma unroll
        for (int i = 0; i < 4; ++i) {
            af[i]  = *(const s8v*)(As + (wm + i * 16 + l15) * 32 + rq);
            bfv[i] = *(const s8v*)(Bs + (wn + i * 16 + l15) * 32 + rq);
        }
#pragma unroll
        for (int mi = 0; mi < 4; ++mi)
#pragma unroll
            for (int ni = 0; ni < 4; ++ni)
                acc[mi][ni] = __builtin_amdgcn_mfma_f32_16x16x32_bf16(
                    af[mi], bfv[ni], acc[mi][ni], 0, 0, 0);
        __syncthreads();
    }

#pragma unroll
    for (int mi = 0; mi < 4; ++mi) {
#pragma unroll
        for (int ni = 0; ni < 4; ++ni) {
            int n = n0 + wn + ni * 16 + l15;
            int sec = n >> 8, hc = n & 255;
            int hh = hc >> 5, c = hc & 31;
            float bv = bias[n];
#pragma unroll
            for (int r = 0; r < 4; ++r) {
                int m = m0 + wm + mi * 16 + quad * 4 + r;
                float v = acc[mi][ni][r] + bv;
                int b = m >> 10, ll2 = m & 1023;
                int bh = b * 8 + hh;
                if (sec == 0)
                    Qb[(size_t)bh * 32768 + ll2 * 32 + c] = f2bf(v * 0.17677669529663687f);
                else if (sec == 1)
                    Kb[(size_t)bh * 32768 + ll2 * 32 + c] = f2bf(v);
                else
                    Vt[(size_t)bh * 32768 + c * 1024 + ll2] = f2bf(v);
            }
        }
    }
}

// ---------------------------------------------------------------------------
// Weight casts fp32 -> bf16
// ---------------------------------------------------------------------------
__global__ __launch_bounds__(256) void castw_kernel(
    const float* __restrict__ W0, const float* __restrict__ W12,
    const float* __restrict__ qkvw, const float* __restrict__ outw,
    const float* __restrict__ f1w, const float* __restrict__ f2w,
    ushort* __restrict__ W0b, ushort* __restrict__ W12b,
    ushort* __restrict__ qkvb, ushort* __restrict__ outb,
    ushort* __restrict__ f1b, ushort* __restrict__ f2b)
{
    int e = (blockIdx.x * 256 + threadIdx.x) * 4;
    if (e >= 2768896) return;
    const float* s; ushort* d; int off;
    if (e < 16384)        { s = W0;   d = W0b;  off = e; }
    else if (e < 147456)  { s = W12;  d = W12b; off = e - 16384; }
    else if (e < 540672)  { s = qkvw; d = qkvb; off = e - 147456; }
    else if (e < 671744)  { s = outw; d = outb; off = e - 540672; }
    else if (e < 1720320) { s = f1w;  d = f1b;  off = e - 671744; }
    else                  { s = f2w;  d = f2b;  off = e - 1720320; }
    float4 v = *(const float4*)(s + off);
    d[off + 0] = f2bf(v.x); d[off + 1] = f2bf(v.y);
    d[off + 2] = f2bf(v.z); d[off + 3] = f2bf(v.w);
}

__global__ __launch_bounds__(256) void castf_kernel(
    const float* __restrict__ s, ushort* __restrict__ d, int n4)
{
    int i = blockIdx.x * 256 + threadIdx.x;
    if (i >= n4) return;
    float4 v = *(const float4*)(s + i * 4);
    d[i * 4 + 0] = f2bf(v.x); d[i * 4 + 1] = f2bf(v.y);
    d[i * 4 + 2] = f2bf(v.z); d[i * 4 + 3] = f2bf(v.w);
}

// ---------------------------------------------------------------------------
// GAT logits
// ---------------------------------------------------------------------------
__global__ __launch_bounds__(256) void asd_kernel(
    const float* __restrict__ h, const float* __restrict__ atts,
    const float* __restrict__ attd, float* __restrict__ a_s, float* __restrict__ a_d)
{
    int idx = blockIdx.x * 256 + threadIdx.x;
    int n = idx >> 3, hh = idx & 7;
    const float* hr = h + (size_t)n * DD + hh * 32;
    const float* sr = atts + hh * 32;
    const float* dr = attd + hh * 32;
    float ss = 0.f, sd = 0.f;
#pragma unroll
    for (int c = 0; c < 32; ++c) { float v = hr[c]; ss += v * sr[c]; sd += v * dr[c]; }
    a_s[idx] = ss; a_d[idx] = sd;
}

// ---------------------------------------------------------------------------
// CSR build
// ---------------------------------------------------------------------------
__global__ void count_kernel(const int* __restrict__ ei, int* __restrict__ deg)
{
    int e = blockIdx.x * 256 + threadIdx.x;
    if (e >= EE + NN) return;
    int d = (e < EE) ? ei[EE + e] : (e - EE);
    atomicAdd(&deg[d], 1);
}

__global__ __launch_bounds__(1024) void scan_kernel(
    const int* __restrict__ deg, int* __restrict__ rowptr, int* __restrict__ cursor)
{
    __shared__ int part[1024];
    int t = threadIdx.x;
    int base = t * 8;
    int loc[8]; int s = 0;
#pragma unroll
    for (int i = 0; i < 8; ++i) { loc[i] = deg[base + i]; s += loc[i]; }
    part[t] = s;
    __syncthreads();
    for (int off = 1; off < 1024; off <<= 1) {
        int v = (t >= off) ? part[t - off] : 0;
        __syncthreads();
        part[t] += v;
        __syncthreads();
    }
    int run = (t == 0) ? 0 : part[t - 1];
#pragma unroll
    for (int i = 0; i < 8; ++i) { rowptr[base + i] = run; cursor[base + i] = run; run += loc[i]; }
    if (t == 1023) rowptr[NN] = run;
}

__global__ void scatter_kernel(const int* __restrict__ ei, int* __restrict__ cursor,
                               int* __restrict__ col)
{
    int e = blockIdx.x * 256 + threadIdx.x;
    if (e >= EE + NN) return;
    int s, d;
    if (e < EE) { s = ei[e]; d = ei[EE + e]; } else { s = e - EE; d = s; }
    int slot = atomicAdd(&cursor[d], 1);
    col[slot] = s;
}

// ---------------------------------------------------------------------------
// GAT aggregation: one wave per dst node; 2 passes (no max subtraction).
// ---------------------------------------------------------------------------
__global__ __launch_bounds__(256) void gat_agg_kernel(
    const float* __restrict__ hlin, const float* __restrict__ a_s,
    const float* __restrict__ a_d, const int* __restrict__ rowptr,
    const int* __restrict__ col, const float* __restrict__ bias,
    float* __restrict__ out, ushort* __restrict__ outb)
{
    int wid = threadIdx.x >> 6, lane = threadIdx.x & 63;
    int dst = blockIdx.x * 4 + wid;
    int start = rowptr[dst], end = rowptr[dst + 1];
    float ad[HH];
#pragma unroll
    for (int h = 0; h < HH; ++h) ad[h] = a_d[(size_t)dst * HH + h];

    float sm[HH];
#pragma unroll
    for (int h = 0; h < HH; ++h) sm[h] = 0.f;
    for (int e = start + lane; e < end; e += 64) {
        int s = col[e];
#pragma unroll
        for (int h = 0; h < HH; ++h) {
            float v = a_s[(size_t)s * HH + h] + ad[h];
            v = v > 0.f ? v : 0.2f * v;
            sm[h] += __expf(v);
        }
    }
#pragma unroll
    for (int h = 0; h < HH; ++h)
#pragma unroll
        for (int off = 32; off; off >>= 1) sm[h] += __shfl_xor(sm[h], off);

    int myh = lane >> 3;
    float sh = sm[myh], adh = ad[myh];
    float4 acc = make_float4(0.f, 0.f, 0.f, 0.f);
    for (int e = start; e < end; ++e) {
        int s = col[e];
        float v = a_s[(size_t)s * HH + myh] + adh;
        v = v > 0.f ? v : 0.2f * v;
        float alpha = __expf(v) / sh;
        float4 hv = *(const float4*)(hlin + (size_t)s * DD + lane * 4);
        acc.x += alpha * hv.x; acc.y += alpha * hv.y;
        acc.z += alpha * hv.z; acc.w += alpha * hv.w;
    }
    float4 bv = *(const float4*)(bias + lane * 4);
    float r0 = fmaxf(acc.x + bv.x, 0.f);
    float r1 = fmaxf(acc.y + bv.y, 0.f);
    float r2 = fmaxf(acc.z + bv.z, 0.f);
    float r3 = fmaxf(acc.w + bv.w, 0.f);
    float* op = out + (size_t)dst * DD + lane * 4;
    op[0] = r0; op[1] = r1; op[2] = r2; op[3] = r3;
    ushort* ob = outb + (size_t)dst * DD + lane * 4;
    ob[0] = f2bf(r0); ob[1] = f2bf(r1); ob[2] = f2bf(r2); ob[3] = f2bf(r3);
}

// ---------------------------------------------------------------------------
// Flash-style MFMA attention, LDS XOR-swizzled.
// Block = 64 q-rows (4 waves x 16) of one bh; 8 chunks of 128 keys.
// ---------------------------------------------------------------------------
__global__ __launch_bounds__(256, 4) void attn_flash_kernel(
    const ushort* __restrict__ Qb, const ushort* __restrict__ Kb,
    const ushort* __restrict__ Vt, ushort* __restrict__ outb)
{
    __shared__ ushort Ks[128 * 32];        // [key][c], chunks swizzled by (row>>1)&3
    __shared__ ushort Vs[32 * 128];        // [c][key], chunks swizzled by row&15
    __shared__ ushort pw[4][16][132];      // per-wave P [qrow][key]

    int t = threadIdx.x;
    int w = t >> 6, lane = t & 63;
    int quad = lane >> 4, l15 = lane & 15;
    int kq = (quad ^ ((l15 >> 1) & 3)) * 8;   // Ks read chunk offset (lane-const)
    int bh = blockIdx.y;
    int q0 = blockIdx.x * 64 + w * 16;
    int b = bh >> 3, h = bh & 7;

    const ushort* qbase = Qb + (size_t)bh * 32768;
    const ushort* kbase = Kb + (size_t)bh * 32768;
    const ushort* vbase = Vt + (size_t)bh * 32768;

    s8v aq = *(const s8v*)(qbase + (q0 + l15) * 32 + quad * 8);

    f32x4 z = {0.f, 0.f, 0.f, 0.f};
    f32x4 o0 = z, o1 = z;
    float m[4] = {-1e30f, -1e30f, -1e30f, -1e30f};
    float lden[4] = {0.f, 0.f, 0.f, 0.f};

    for (int ch = 0; ch < 8; ++ch) {
        int j0 = ch * 128;
#pragma unroll
        for (int i = 0; i < 2; ++i) {
            int idx = i * 256 + t;
            // K: 128 rows x 4 chunks, source chunk q ^ ((r>>1)&3)
            int kr = idx >> 2, kc = idx & 3;
            int kcs = (kc ^ ((kr >> 1) & 3)) * 8;
            __builtin_amdgcn_global_load_lds(
                (const __attribute__((address_space(1))) unsigned int*)
                    (kbase + (size_t)(j0 + kr) * 32 + kcs),
                (__attribute__((address_space(3))) unsigned int*)(Ks + idx * 8), 16, 0, 0);
            // V: 32 rows x 16 chunks, source chunk q ^ (r&15)
            int vr = idx >> 4, vc = idx & 15;
            int vcs = (vc ^ (vr & 15)) * 8;
            __builtin_amdgcn_global_load_lds(
                (const __attribute__((address_space(1))) unsigned int*)
                    (vbase + (size_t)vr * 1024 + j0 + vcs),
                (__attribute__((address_space(3))) unsigned int*)(Vs + idx * 8), 16, 0, 0);
        }
        __syncthreads();

        // QK^T
        f32x4 s[8];
#pragma unroll
        for (int kk = 0; kk < 8; ++kk) {
            s8v bk = *(const s8v*)(Ks + (kk * 16 + l15) * 32 + kq);
            s[kk] = __builtin_amdgcn_mfma_f32_16x16x32_bf16(aq, bk, z, 0, 0, 0);
        }

        // online softmax update
        float cs[4], sc[4];
#pragma unroll
        for (int r = 0; r < 4; ++r) {
            float v = s[0][r];
#pragma unroll
            for (int kk = 1; kk < 8; ++kk) v = fmaxf(v, s[kk][r]);
#pragma unroll
            for (int off = 1; off < 16; off <<= 1) v = fmaxf(v, __shfl_xor(v, off));
            float mn = fmaxf(m[r], v);
            sc[r] = __expf(m[r] - mn);
            m[r] = mn;
            cs[r] = 0.f;
        }
#pragma unroll
        for (int kk = 0; kk < 8; ++kk) {
#pragma unroll
            for (int r = 0; r < 4; ++r) {
                float p = __expf(s[kk][r] - m[r]);
                cs[r] += p;
                pw[w][quad * 4 + r][kk * 16 + l15] = f2bf(p);
            }
        }
#pragma unroll
        for (int r = 0; r < 4; ++r) {
#pragma unroll
            for (int off = 1; off < 16; off <<= 1) cs[r] += __shfl_xor(cs[r], off);
            lden[r] = lden[r] * sc[r] + cs[r];
            o0[r] *= sc[r];
            o1[r] *= sc[r];
        }

        // PV (Vs chunks swizzled by row&15 = l15)
#pragma unroll
        for (int kk = 0; kk < 4; ++kk) {
            s8v ap = *(const s8v*)(&pw[w][l15][kk * 32 + quad * 8]);
            int c0 = ((kk * 4 + quad) ^ l15) * 8;
            s8v b0 = *(const s8v*)(Vs + (size_t)l15 * 128 + c0);
            s8v b1 = *(const s8v*)(Vs + (size_t)(16 + l15) * 128 + c0);
            o0 = __builtin_amdgcn_mfma_f32_16x16x32_bf16(ap, b0, o0, 0, 0, 0);
            o1 = __builtin_amdgcn_mfma_f32_16x16x32_bf16(ap, b1, o1, 0, 0, 0);
        }
        __syncthreads();
    }

#pragma unroll
    for (int r = 0; r < 4; ++r) {
        int row = q0 + quad * 4 + r;
        float inv = 1.f / lden[r];
        outb[(size_t)(b * 1024 + row) * 256 + h * 32 + l15]      = f2bf(o0[r] * inv);
        outb[(size_t)(b * 1024 + row) * 256 + h * 32 + 16 + l15] = f2bf(o1[r] * inv);
    }
}

// ---------------------------------------------------------------------------
// LayerNorm in place (fp32) + bf16 copy out.
// ---------------------------------------------------------------------------
__global__ __launch_bounds__(256) void ln_kernel(
    float* __restrict__ x, const float* __restrict__ w, const float* __restrict__ b,
    ushort* __restrict__ xb)
{
    int wid = threadIdx.x >> 6, lane = threadIdx.x & 63;
    size_t row = blockIdx.x * 4 + wid;
    float4 v = *(float4*)(x + row * DD + lane * 4);
    float s = v.x + v.y + v.z + v.w;
#pragma unroll
    for (int off = 32; off; off >>= 1) s += __shfl_xor(s, off);
    float mu = s * (1.f / 256.f);
    float dx = v.x - mu, dy = v.y - mu, dz = v.z - mu, dw = v.w - mu;
    float q = dx * dx + dy * dy + dz * dz + dw * dw;
#pragma unroll
    for (int off = 32; off; off >>= 1) q += __shfl_xor(q, off);
    float rstd = rsqrtf(q * (1.f / 256.f) + 1e-5f);
    int c = lane * 4;
    float4 wv = *(const float4*)(w + c);
    float4 bv = *(const float4*)(b + c);
    float4 o;
    o.x = dx * rstd * wv.x + bv.x;
    o.y = dy * rstd * wv.y + bv.y;
    o.z = dz * rstd * wv.z + bv.z;
    o.w = dw * rstd * wv.w + bv.w;
    *(float4*)(x + row * DD + c) = o;
    ushort* ob = xb + row * DD + c;
    ob[0] = f2bf(o.x); ob[1] = f2bf(o.y); ob[2] = f2bf(o.z); ob[3] = f2bf(o.w);
}

// ---------------------------------------------------------------------------
// Prediction head: one thread per row, 3 outputs.
// ---------------------------------------------------------------------------
__global__ __launch_bounds__(256) void pred_kernel(
    const float* __restrict__ x, const float* __restrict__ w,
    const float* __restrict__ b, float* __restrict__ out)
{
    int m = blockIdx.x * 256 + threadIdx.x;   // 8192
    const float* xr = x + (size_t)m * DD;
    float s0 = b[0], s1 = b[1], s2 = b[2];
#pragma unroll 4
    for (int c = 0; c < DD; c += 4) {
        float4 xv = *(const float4*)(xr + c);
        float4 w0 = *(const float4*)(w + c);
        float4 w1 = *(const float4*)(w + DD + c);
        float4 w2 = *(const float4*)(w + 2 * DD + c);
        s0 += xv.x * w0.x + xv.y * w0.y + xv.z * w0.z + xv.w * w0.w;
        s1 += xv.x * w1.x + xv.y * w1.y + xv.z * w1.z + xv.w * w1.w;
        s2 += xv.x * w2.x + xv.y * w2.y + xv.z * w2.z + xv.w * w2.w;
    }
    out[m * 3 + 0] = s0;
    out[m * 3 + 1] = s1;
    out[m * 3 + 2] = s2;
}

// ---------------------------------------------------------------------------
extern "C" void kernel_launch(void* const* d_in, const int* in_sizes, int n_in,
                              void* d_out, int out_size, void* d_ws, size_t ws_size,
                              hipStream_t stream)
{
    const float* x        = (const float*)d_in[0];
    const int*   ei       = (const int*)d_in[1];
    const float* gat_W0   = (const float*)d_in[3];
    const float* gat_W12  = (const float*)d_in[4];
    const float* att_src  = (const float*)d_in[5];
    const float* att_dst  = (const float*)d_in[6];
    const float* gat_bias = (const float*)d_in[7];
    const float* qkv_w    = (const float*)d_in[8];
    const float* qkv_b    = (const float*)d_in[9];
    const float* out_w    = (const float*)d_in[10];
    const float* out_b    = (const float*)d_in[11];
    const float* ln1_w    = (const float*)d_in[12];
    const float* ln1_b    = (const float*)d_in[13];
    const float* ln2_w    = (const float*)d_in[14];
    const float* ln2_b    = (const float*)d_in[15];
    const float* ff1_w    = (const float*)d_in[16];
    const float* ff1_b    = (const float*)d_in[17];
    const float* ff2_w    = (const float*)d_in[18];
    const float* ff2_b    = (const float*)d_in[19];
    const float* pred_w   = (const float*)d_in[20];
    const float* pred_b   = (const float*)d_in[21];
    float* outp = (float*)d_out;

    float* ws   = (float*)d_ws;
    float* hA   = ws;                                    // [8192,256] f32
    float* hB   = ws + 2097152;                          // [8192,256] f32
    ushort* ffb  = (ushort*)(ws + 4194304);              // [8192,2048] bf16
    ushort* Qb   = (ushort*)(ws + 12582912);             // [64][1024][32]
    ushort* Kb   = (ushort*)(ws + 13631488);
    ushort* Vt   = (ushort*)(ws + 14680064);             // [64][32][1024]
    ushort* attnb= (ushort*)(ws + 15728640);             // [8192,256] bf16
    ushort* lnb  = (ushort*)(ws + 16777216);             // [8192,256] bf16
    ushort* hBb  = (ushort*)(ws + 17825792);             // [8192,256] bf16
    ushort* xb   = (ushort*)(ws + 18874368);             // [8192,64] bf16
    ushort* wbase= (ushort*)(ws + 19136512);
    ushort* W0b    = wbase;
    ushort* W12b   = wbase + 16384;
    ushort* qkv_wb = wbase + 147456;
    ushort* out_wb = wbase + 540672;
    ushort* ff1_wb = wbase + 671744;
    ushort* ff2_wb = wbase + 1720320;
    float* a_s  = ws + 20520960;
    float* a_d  = ws + 20586496;
    int*   iw   = (int*)(ws + 20652032);
    int*   deg    = iw;
    int*   rowptr = iw + 8192;
    int*   cursor = iw + 16392;
    int*   col    = iw + 24592;

    // ---- casts ----
    castw_kernel<<<2705, 256, 0, stream>>>(gat_W0, gat_W12, qkv_w, out_w, ff1_w, ff2_w,
                                           W0b, W12b, qkv_wb, out_wb, ff1_wb, ff2_wb);
    castf_kernel<<<512, 256, 0, stream>>>(x, xb, 131072);

    // ---- CSR build ----
    hipMemsetAsync(deg, 0, NN * sizeof(int), stream);
    int etot = EE + NN;
    count_kernel<<<(etot + 255) / 256, 256, 0, stream>>>(ei, deg);
    scan_kernel<<<1, 1024, 0, stream>>>(deg, rowptr, cursor);
    scatter_kernel<<<(etot + 255) / 256, 256, 0, stream>>>(ei, cursor, col);

    // ---- GAT layer 0 ----
    mgemm_kernel<false, false, false, true, false><<<dim3(64, 2), 256, 0, stream>>>(
        xb, W0b, nullptr, nullptr, hA, nullptr, NN, DD, 64);
    asd_kernel<<<256, 256, 0, stream>>>(hA, att_src, att_dst, a_s, a_d);
    gat_agg_kernel<<<2048, 256, 0, stream>>>(hA, a_s, a_d, rowptr, col, gat_bias, hB, hBb);

    // ---- GAT layers 1,2 ----
    for (int l = 0; l < 2; ++l) {
        mgemm_kernel<false, false, false, true, false><<<dim3(64, 2), 256, 0, stream>>>(
            hBb, W12b + (size_t)l * DD * DD, nullptr, nullptr, hA, nullptr, NN, DD, DD);
        asd_kernel<<<256, 256, 0, stream>>>(
            hA, att_src + (l + 1) * 256, att_dst + (l + 1) * 256, a_s, a_d);
        gat_agg_kernel<<<2048, 256, 0, stream>>>(
            hA, a_s, a_d, rowptr, col, gat_bias + (l + 1) * 256, hB, hBb);
    }

    // ---- Transformer layers ----
    for (int l = 0; l < 2; ++l) {
        mgemm_qkv_kernel<<<dim3(64, 6), 256, 0, stream>>>(
            hBb, qkv_wb + (size_t)l * 768 * DD, qkv_b + l * 768, Qb, Kb, Vt, NN, DD);
        attn_flash_kernel<<<dim3(16, 64), 256, 0, stream>>>(Qb, Kb, Vt, attnb);
        mgemm_kernel<true, false, true, true, false><<<dim3(64, 2), 256, 0, stream>>>(
            attnb, out_wb + (size_t)l * DD * DD, out_b + l * DD, hB,
            hA, nullptr, NN, DD, DD);
        ln_kernel<<<2048, 256, 0, stream>>>(hA, ln1_w + l * DD, ln1_b + l * DD, lnb);
        mgemm_kernel<true, true, false, false, true><<<dim3(64, 16), 256, 0, stream>>>(
            lnb, ff1_wb + (size_t)l * DFFN * DD, ff1_b + l * DFFN, nullptr,
            nullptr, ffb, NN, DFFN, DD);
        mgemm_kernel<true, false, true, true, false><<<dim3(64, 2), 256, 0, stream>>>(
            ffb, ff2_wb + (size_t)l * DD * DFFN, ff2_b + l * DD, hA,
            hB, nullptr, NN, DD, DFFN);
        ln_kernel<<<2048, 256, 0, stream>>>(hB, ln2_w + l * DD, ln2_b + l * DD, hBb);
    }

    // ---- prediction head ----
    pred_kernel<<<32, 256, 0, stream>>>(hB, pred_w, pred_b, outp);
}